// Round 2
// baseline (716.079 us; speedup 1.0000x reference)
//
#include <hip/hip_runtime.h>

// FNO3d forward, MI355X. Round 8:
//  - k_fH deleted: k_liftA/k_ptA now cover a full (b,dx) plane with 1024
//    threads, keep the W-DFT tail results in LDS (As, 16KB), and do the
//    ky-DFT in-block (DPP quad_perm 4-lane reduce), writing Bh directly.
//    A-buffer (8.4MB w + r) and 4 dispatches disappear; Ps redundancy (x4)
//    in old k_ptA disappears.
//  - k_fDmix: dx-sum split 4-way across a 1024-thread block (quad reduce),
//    cutting its serial depth 4x.
//  - Launches: 15 -> 10.
//
// Layouts:
//   x  : float [B=8][C=8][64][64][64]          (67,108,864 B)
//   Bh : float2[8][8][dx=64][ky=8][kz=4]      ( 1,048,576 B)
//   O  : float2[8][8][kx=8][ky=8][kz=4]      (   131,072 B)

#define TWO_PI_OVER_64 0.09817477042468103

__device__ __forceinline__ float gelu_fast(float x) {
    float x2 = x * x;
    float p  = x * (1.0f + 0.044715f * x2);
    float e  = __builtin_amdgcn_exp2f(-2.3022083f * p);
    return x * __builtin_amdgcn_rcpf(1.0f + e);
}

#define BUILD_TW() \
    __shared__ float twc[64], tws[64]; \
    if (threadIdx.x < 64) { \
        double a_ = TWO_PI_OVER_64 * (double)threadIdx.x; \
        twc[threadIdx.x] = (float)cos(a_); tws[threadIdx.x] = (float)sin(a_); \
    }

// DPP row_ror rotation-add: after steps 1,2,4,8 every lane of each 16-lane
// row holds the row sum. VALU-only.
#define ROR_STEP(x, CTRL) \
    x += __int_as_float(__builtin_amdgcn_update_dpp( \
            0, __float_as_int(x), CTRL, 0xF, 0xF, true))

__device__ __forceinline__ float red16_ror(float x) {
    ROR_STEP(x, 0x121);   // row_ror:1
    ROR_STEP(x, 0x122);   // row_ror:2
    ROR_STEP(x, 0x124);   // row_ror:4
    ROR_STEP(x, 0x128);   // row_ror:8
    return x;
}

// 4-lane (quad) reduce: quad_perm [1,0,3,2] then [2,3,0,1].
__device__ __forceinline__ float red4_quad(float x) {
    x += __int_as_float(__builtin_amdgcn_update_dpp(
            0, __float_as_int(x), 0xB1, 0xF, 0xF, true));
    x += __int_as_float(__builtin_amdgcn_update_dpp(
            0, __float_as_int(x), 0x4E, 0xF, 0xF, true));
    return x;
}

// A-tail (LDS dest): partial W-DFT over 4 w-points, DPP reduce across the 16
// wq-lanes, predicated float4 store into As row (wq=0 -> kz0/1, wq=1 -> kz2/3).
__device__ __forceinline__ void a_tail_lds(
    const float v[4], const float c1[4], const float s1[4],
    const float c2[4], const float s2[4], const float c3[4], const float s3[4],
    int wq, float2* __restrict__ AsRow)
{
    float p0  = v[0] + v[1] + v[2] + v[3];
    float ar1 = v[0]*c1[0] + v[1]*c1[1] + v[2]*c1[2] + v[3]*c1[3];
    float ai1 = -(v[0]*s1[0] + v[1]*s1[1] + v[2]*s1[2] + v[3]*s1[3]);
    float ar2 = v[0]*c2[0] + v[1]*c2[1] + v[2]*c2[2] + v[3]*c2[3];
    float ai2 = -(v[0]*s2[0] + v[1]*s2[1] + v[2]*s2[2] + v[3]*s2[3]);
    float ar3 = v[0]*c3[0] + v[1]*c3[1] + v[2]*c3[2] + v[3]*c3[3];
    float ai3 = -(v[0]*s3[0] + v[1]*s3[1] + v[2]*s3[2] + v[3]*s3[3]);
    p0  = red16_ror(p0);
    ar1 = red16_ror(ar1);  ai1 = red16_ror(ai1);
    ar2 = red16_ror(ar2);  ai2 = red16_ror(ai2);
    ar3 = red16_ror(ar3);  ai3 = red16_ror(ai3);
    if (wq < 2) {
        float4 av;
        av.x = (wq == 0) ? p0   : ar2;
        av.y = (wq == 0) ? 0.f  : ai2;
        av.z = (wq == 0) ? ar1  : ar3;
        av.w = (wq == 0) ? ai1  : ai3;
        *((float4*)AsRow + wq) = av;
    }
}

// In-block ky-DFT over the LDS A-plane -> Bh[b,c,dx,ky,kz].
// 1024 threads: out = t>>2 (c,ky,kz), q = t&3 sums dy = q,q+4,... (16 terms,
// stride-4 keeps LDS banks spread), quad reduce, lane q==0 writes.
__device__ __forceinline__ void ky_dft_store(
    const float2* __restrict__ As, const float* __restrict__ twc,
    const float* __restrict__ tws, int t, int b, int dx,
    float2* __restrict__ Bh)
{
    const int out = t >> 2, q = t & 3;
    const int c = out >> 5, ky = (out >> 2) & 7, kz = out & 3;
    const int kyv = ky < 4 ? ky : ky + 56;
    float re = 0.f, im = 0.f;
    int ti = (kyv * q) & 63;
    const int step = (kyv * 4) & 63;
    #pragma unroll 4
    for (int i = 0; i < 16; ++i) {
        int dy = q + i * 4;
        float2 a = As[(c * 64 + dy) * 4 + kz];
        float cc = twc[ti], ss = tws[ti];
        re += a.x * cc + a.y * ss;   // * e^{-i phi}
        im += a.y * cc - a.x * ss;
        ti = (ti + step) & 63;
    }
    re = red4_quad(re);
    im = red4_quad(im);
    if (q == 0)
        Bh[(size_t)(b * 8 + c) * 2048 + dx * 32 + ky * 4 + kz] =
            make_float2(re, im);
}

// ---------------------------------------------------------------------------
// Lift (3->8 ch) + forward W-DFT (DPP tail, LDS) + in-block ky-DFT -> Bh.
// grid 512 = b(8)*dx(64); block 1024 (dyl = t>>4 in 0..63, wq = t&15).
// ---------------------------------------------------------------------------
__global__ __launch_bounds__(1024, 8) void k_liftA2(
    const float* __restrict__ u, const float* __restrict__ fc0w,
    const float* __restrict__ fc0b, float* __restrict__ x,
    float2* __restrict__ Bh)
{
    BUILD_TW();
    __shared__ float2 As[8 * 64 * 4];   // [c][dy][kz], 16KB
    const int t = threadIdx.x, bid = blockIdx.x;
    const int b = bid >> 6, dx = bid & 63;
    const int dyl = t >> 4, wq = t & 15;
    const size_t sp = (size_t)dx * 4096 + (size_t)dyl * 64 + wq * 4;
    float uin[3][4];
    #pragma unroll
    for (int c = 0; c < 3; ++c) {
        float4 v = *(const float4*)&u[(size_t)(b * 3 + c) * 262144 + sp];
        uin[c][0] = v.x; uin[c][1] = v.y; uin[c][2] = v.z; uin[c][3] = v.w;
    }
    __syncthreads();
    float c1[4], s1[4], c2[4], s2[4], c3[4], s3[4];
    #pragma unroll
    for (int j = 0; j < 4; ++j) {
        int w = wq * 4 + j;
        c1[j] = twc[w];             s1[j] = tws[w];
        c2[j] = twc[(2 * w) & 63];  s2[j] = tws[(2 * w) & 63];
        c3[j] = twc[(3 * w) & 63];  s3[j] = tws[(3 * w) & 63];
    }
    #pragma unroll
    for (int o = 0; o < 8; ++o) {
        float w0 = fc0w[o * 3 + 0], w1 = fc0w[o * 3 + 1], w2 = fc0w[o * 3 + 2];
        float bb = fc0b[o];
        float v[4];
        #pragma unroll
        for (int j = 0; j < 4; ++j)
            v[j] = bb + uin[0][j] * w0 + uin[1][j] * w1 + uin[2][j] * w2;
        *(float4*)&x[(size_t)(b * 8 + o) * 262144 + sp] =
            make_float4(v[0], v[1], v[2], v[3]);
        a_tail_lds(v, c1, s1, c2, s2, c3, s3, wq, &As[(o * 64 + dyl) * 4]);
    }
    __syncthreads();
    ky_dft_store(As, twc, tws, t, b, dx, Bh);
}

// ---------------------------------------------------------------------------
// D-axis DFT (dx-sum split 4-way, quad reduce) + spectral mix.
// grid 64 = b(8)*kx(8); block 1024.
// ---------------------------------------------------------------------------
__global__ __launch_bounds__(1024) void k_fDmix(
    const float2* __restrict__ Bh,
    const float2* __restrict__ w1, const float2* __restrict__ w2,
    const float2* __restrict__ w3, const float2* __restrict__ w4,
    float2* __restrict__ O)
{
    BUILD_TW();
    __shared__ float2 Cs[256];   // [c][ky][kz] = c*32 + ky*4 + kz
    const int t = threadIdx.x, bid = blockIdx.x;
    const int b = bid >> 3, kx = bid & 7;
    const int kxv = kx < 4 ? kx : kx + 56;
    __syncthreads();
    {
        const int out = t >> 2, q = t & 3;
        const int kz = out & 3, ky = (out >> 2) & 7, c = out >> 5;
        const float2* Bp = Bh + (size_t)(b * 8 + c) * 2048 + ky * 4 + kz;
        float re = 0.f, im = 0.f;
        int ti = (kxv * q) & 63;
        const int step = (kxv * 4) & 63;
        #pragma unroll 4
        for (int i = 0; i < 16; ++i) {
            float2 v = Bp[(q + i * 4) * 32];
            float cc = twc[ti], ss = tws[ti];
            re += v.x * cc + v.y * ss;
            im += v.y * cc - v.x * ss;
            ti = (ti + step) & 63;
        }
        re = red4_quad(re);
        im = red4_quad(im);
        if (q == 0) Cs[out] = make_float2(re, im);
    }
    __syncthreads();
    if (t < 256) {
        int kz = t & 3, ky = (t >> 2) & 7, o = t >> 5;
        const float2* wsel = (kx < 4) ? ((ky < 4) ? w1 : w3) : ((ky < 4) ? w2 : w4);
        int kxw = kx & 3, kyw = ky & 3;
        float re = 0.f, im = 0.f;
        #pragma unroll
        for (int i = 0; i < 8; ++i) {
            float2 cv = Cs[i * 32 + ky * 4 + kz];
            float2 wv = wsel[(((size_t)(i * 8 + o) * 4 + kxw) * 4 + kyw) * 4 + kz];
            re += cv.x * wv.x - cv.y * wv.y;
            im += cv.x * wv.y + cv.y * wv.x;
        }
        O[(((size_t)(b * 8 + o) * 8 + kx) * 8 + ky) * 4 + kz] = make_float2(re, im);
    }
}

// ---------------------------------------------------------------------------
// Inverse D/H DFT in LDS + irfftW + conv + gelu + x in place + W-DFT tail to
// LDS + in-block ky-DFT -> Bh. grid 512 = b(8)*dx(64); block 1024.
// ---------------------------------------------------------------------------
__global__ __launch_bounds__(1024, 8) void k_ptA2(
    float* __restrict__ x, const float2* __restrict__ O,
    const float* __restrict__ cw, const float* __restrict__ cb,
    float2* __restrict__ Bh)
{
    BUILD_TW();
    __shared__ float2 Ps[256];          // [o][ky][kz]
    __shared__ float2 Qs[8 * 64 * 4];   // [o][dy][kz], 16KB
    __shared__ float2 As[8 * 64 * 4];   // [o][dy][kz], 16KB
    const int t = threadIdx.x, bid = blockIdx.x;
    const int b = bid >> 6, dx = bid & 63;
    const int dyl = t >> 4, wq = t & 15;
    const size_t sp = (size_t)dx * 4096 + (size_t)dyl * 64 + wq * 4;
    // ---- prefetch: all global loads issued before any barrier ----
    float4 xv[8];
    #pragma unroll
    for (int c = 0; c < 8; ++c)
        xv[c] = *(const float4*)&x[(size_t)(b * 8 + c) * 262144 + sp];
    float2 ov[8];
    if (t < 256) {
        const int pkz = t & 3, pky = (t >> 2) & 7, po = t >> 5;
        #pragma unroll
        for (int kxi = 0; kxi < 8; ++kxi)
            ov[kxi] = O[(((size_t)(b * 8 + po) * 8 + kxi) * 8 + pky) * 4 + pkz];
    }
    __syncthreads();
    if (t < 256) {   // Ps: inverse D-DFT of O at this dx
        float re = 0.f, im = 0.f;
        #pragma unroll
        for (int kxi = 0; kxi < 8; ++kxi) {
            int kxv = kxi < 4 ? kxi : kxi + 56;
            int ti = (kxv * dx) & 63;
            float cc = twc[ti], ss = tws[ti];
            re += ov[kxi].x * cc - ov[kxi].y * ss;   // * e^{+i phi}
            im += ov[kxi].y * cc + ov[kxi].x * ss;
        }
        Ps[t] = make_float2(re, im);
    }
    __syncthreads();
    #pragma unroll
    for (int it = t; it < 2048; it += 1024) {   // Qs: inverse H-DFT
        int kz = it & 3, dy = (it >> 2) & 63, o = it >> 8;
        float re = 0.f, im = 0.f;
        #pragma unroll
        for (int kyi = 0; kyi < 8; ++kyi) {
            int kyv = kyi < 4 ? kyi : kyi + 56;
            int ti = (kyv * dy) & 63;
            float2 v = Ps[(o * 8 + kyi) * 4 + kz];
            float cc = twc[ti], ss = tws[ti];
            re += v.x * cc - v.y * ss;
            im += v.y * cc + v.x * ss;
        }
        Qs[(o * 64 + dy) * 4 + kz] = make_float2(re, im);
    }
    __syncthreads();
    float c1[4], s1[4], c2[4], s2[4], c3[4], s3[4];
    #pragma unroll
    for (int j = 0; j < 4; ++j) {
        int w = wq * 4 + j;
        c1[j] = twc[w];             s1[j] = tws[w];
        c2[j] = twc[(2 * w) & 63];  s2[j] = tws[(2 * w) & 63];
        c3[j] = twc[(3 * w) & 63];  s3[j] = tws[(3 * w) & 63];
    }
    const float invN3 = 1.0f / 262144.0f;
    #pragma unroll
    for (int o = 0; o < 8; ++o) {
        float4 qa = *(const float4*)&Qs[(o * 64 + dyl) * 4];      // q0,q1
        float4 qb = *(const float4*)&Qs[(o * 64 + dyl) * 4 + 2];  // q2,q3
        float outj[4];
        #pragma unroll
        for (int j = 0; j < 4; ++j) {
            float x1 = qa.x + 2.f * (qa.z * c1[j] - qa.w * s1[j]
                                   + qb.x * c2[j] - qb.y * s2[j]
                                   + qb.z * c3[j] - qb.w * s3[j]);
            x1 *= invN3;
            float x2 = cb[o];
            #pragma unroll
            for (int c = 0; c < 8; ++c) {
                const float* xc = &xv[c].x;
                x2 += cw[o * 8 + c] * xc[j];
            }
            outj[j] = gelu_fast(x1 + x2);
        }
        *(float4*)&x[(size_t)(b * 8 + o) * 262144 + sp] =
            make_float4(outj[0], outj[1], outj[2], outj[3]);
        a_tail_lds(outj, c1, s1, c2, s2, c3, s3, wq, &As[(o * 64 + dyl) * 4]);
    }
    __syncthreads();
    ky_dft_store(As, twc, tws, t, b, dx, Bh);
}

// ---------------------------------------------------------------------------
// Layer 3: inverse DFT + conv (no gelu) -> fc1+gelu+fc2, + hard core u*nu.
// Writes d_out only; x/u prefetched at top. grid 2048; block 256.
// ---------------------------------------------------------------------------
__global__ __launch_bounds__(256, 4) void k_ptout(
    const float* __restrict__ x, const float2* __restrict__ O,
    const float* __restrict__ cw, const float* __restrict__ cb,
    const float* __restrict__ u, const float* __restrict__ nu,
    const float* __restrict__ fc1w, const float* __restrict__ fc1b,
    const float* __restrict__ fc2w, const float* __restrict__ fc2b,
    float* __restrict__ out)
{
    BUILD_TW();
    __shared__ float2 Ps[256];
    __shared__ float2 Qs[8 * 16 * 4];
    const int t = threadIdx.x, bid = blockIdx.x;
    const int b = bid >> 8, dx = (bid >> 2) & 63, dy0 = (bid & 3) * 16;
    const int dyl = t >> 4, wq = t & 15;
    const size_t sp = (size_t)dx * 4096 + (size_t)(dy0 + dyl) * 64 + wq * 4;
    float4 xv[8];
    #pragma unroll
    for (int c = 0; c < 8; ++c)
        xv[c] = *(const float4*)&x[(size_t)(b * 8 + c) * 262144 + sp];
    float4 uv[3];
    #pragma unroll
    for (int c = 0; c < 3; ++c)
        uv[c] = *(const float4*)&u[(size_t)(b * 3 + c) * 262144 + sp];
    const int pkz = t & 3, pky = (t >> 2) & 7, po = t >> 5;
    float2 ovv[8];
    #pragma unroll
    for (int kxi = 0; kxi < 8; ++kxi)
        ovv[kxi] = O[(((size_t)(b * 8 + po) * 8 + kxi) * 8 + pky) * 4 + pkz];
    __syncthreads();
    {
        float re = 0.f, im = 0.f;
        #pragma unroll
        for (int kxi = 0; kxi < 8; ++kxi) {
            int kxv = kxi < 4 ? kxi : kxi + 56;
            int ti = (kxv * dx) & 63;
            float cc = twc[ti], ss = tws[ti];
            re += ovv[kxi].x * cc - ovv[kxi].y * ss;
            im += ovv[kxi].y * cc + ovv[kxi].x * ss;
        }
        Ps[t] = make_float2(re, im);
    }
    __syncthreads();
    for (int it = t; it < 512; it += 256) {
        int kz = it & 3, qdyl = (it >> 2) & 15, o = it >> 6;
        int dy = dy0 + qdyl;
        float re = 0.f, im = 0.f;
        #pragma unroll
        for (int kyi = 0; kyi < 8; ++kyi) {
            int kyv = kyi < 4 ? kyi : kyi + 56;
            int ti = (kyv * dy) & 63;
            float2 v = Ps[(o * 8 + kyi) * 4 + kz];
            float cc = twc[ti], ss = tws[ti];
            re += v.x * cc - v.y * ss;
            im += v.y * cc + v.x * ss;
        }
        Qs[(o * 16 + qdyl) * 4 + kz] = make_float2(re, im);
    }
    __syncthreads();
    float c1[4], s1[4], c2[4], s2[4], c3[4], s3[4];
    #pragma unroll
    for (int j = 0; j < 4; ++j) {
        int w = wq * 4 + j;
        c1[j] = twc[w];             s1[j] = tws[w];
        c2[j] = twc[(2 * w) & 63];  s2[j] = tws[(2 * w) & 63];
        c3[j] = twc[(3 * w) & 63];  s3[j] = tws[(3 * w) & 63];
    }
    const float invN3 = 1.0f / 262144.0f;
    float vv[8][4];   // layer-3 activations (no gelu)
    #pragma unroll
    for (int o = 0; o < 8; ++o) {
        float4 qa = *(const float4*)&Qs[(o * 16 + dyl) * 4];
        float4 qb = *(const float4*)&Qs[(o * 16 + dyl) * 4 + 2];
        #pragma unroll
        for (int j = 0; j < 4; ++j) {
            float x1 = qa.x + 2.f * (qa.z * c1[j] - qa.w * s1[j]
                                   + qb.x * c2[j] - qb.y * s2[j]
                                   + qb.z * c3[j] - qb.w * s3[j]);
            x1 *= invN3;
            float x2 = cb[o];
            #pragma unroll
            for (int c = 0; c < 8; ++c) {
                const float* xc = &xv[c].x;
                x2 += cw[o * 8 + c] * xc[j];
            }
            vv[o][j] = x1 + x2;
        }
    }
    float so[6][4];
    #pragma unroll
    for (int c6 = 0; c6 < 6; ++c6)
        #pragma unroll
        for (int j = 0; j < 4; ++j) so[c6][j] = fc2b[c6];
    #pragma unroll 4
    for (int h = 0; h < 32; ++h) {
        float wr[8];
        #pragma unroll
        for (int c = 0; c < 8; ++c) wr[c] = fc1w[h * 8 + c];   // uniform -> SGPR
        const float hb = fc1b[h];
        float w2r[6];
        #pragma unroll
        for (int c6 = 0; c6 < 6; ++c6) w2r[c6] = fc2w[c6 * 32 + h];
        #pragma unroll
        for (int j = 0; j < 4; ++j) {
            float a = hb;
            #pragma unroll
            for (int c = 0; c < 8; ++c) a += vv[c][j] * wr[c];
            float g = gelu_fast(a);
            #pragma unroll
            for (int c6 = 0; c6 < 6; ++c6) so[c6][j] += g * w2r[c6];
        }
    }
    const float nuv = nu[0];
    #pragma unroll
    for (int c6 = 0; c6 < 6; ++c6) {
        float4 res;
        float* rp = &res.x;
        if (c6 < 3) {
            const float* up = &uv[c6].x;
            #pragma unroll
            for (int j = 0; j < 4; ++j) rp[j] = 0.3f * so[c6][j] + up[j] * nuv;
        } else {
            #pragma unroll
            for (int j = 0; j < 4; ++j) rp[j] = 0.3f * so[c6][j];
        }
        *(float4*)&out[(size_t)(b * 6 + c6) * 262144 + sp] = res;
    }
}

// pack split re/im spectral leaves into interleaved float2, ALL 16 weights
// in one dispatch (pointers passed by value).
struct PackPtrs { const float* re[16]; const float* im[16]; };

__global__ __launch_bounds__(256) void k_pack_all(PackPtrs p, float2* __restrict__ dst)
{
    int i = blockIdx.x * 256 + threadIdx.x;   // 65536 = 16 * 4096
    int w = i >> 12, idx = i & 4095;
    dst[i] = make_float2(p.re[w][idx], p.im[w][idx]);
}

// ---------------------------------------------------------------------------
extern "C" void kernel_launch(void* const* d_in, const int* in_sizes, int n_in,
                              void* d_out, int out_size, void* d_ws, size_t ws_size,
                              hipStream_t stream)
{
    (void)out_size;
    const char* leaf[32];
    bool spec_split = false;
    const char* spec_re[16]; const char* spec_im[16];
    int src = 0;
    leaf[0] = (const char*)d_in[src++];
    leaf[1] = (const char*)d_in[src++];
    leaf[2] = (const char*)d_in[src++];
    leaf[3] = (const char*)d_in[src++];
    {
        int s = (src < n_in) ? in_sizes[src] : 4096;
        if (n_in >= 48 && s == 4096) {
            spec_split = true;
            for (int i = 0; i < 16; ++i) {
                spec_re[i] = (const char*)d_in[src++];
                spec_im[i] = (const char*)d_in[src++];
            }
        } else {
            int per;
            if (s == 4096 || s == 8192) per = 1;
            else if (s == 16384 || s == 32768) per = 4;
            else per = 16;
            for (int i = 0; i < 16; i += per) {
                const char* base = (const char*)d_in[src++];
                for (int j = 0; j < per; ++j) leaf[4 + i + j] = base + (size_t)j * 4096 * 8;
            }
        }
    }
    {
        int s = (src < n_in) ? in_sizes[src] : 64;
        if (s == 64) { for (int i = 0; i < 4; ++i) leaf[20 + i] = (const char*)d_in[src++]; }
        else { const char* base = (const char*)d_in[src++];
               for (int i = 0; i < 4; ++i) leaf[20 + i] = base + (size_t)i * 64 * 4; }
    }
    {
        int s = (src < n_in) ? in_sizes[src] : 8;
        if (s == 8) { for (int i = 0; i < 4; ++i) leaf[24 + i] = (const char*)d_in[src++]; }
        else { const char* base = (const char*)d_in[src++];
               for (int i = 0; i < 4; ++i) leaf[24 + i] = base + (size_t)i * 8 * 4; }
    }
    leaf[28] = (const char*)d_in[src++];
    leaf[29] = (const char*)d_in[src++];
    leaf[30] = (const char*)d_in[src++];
    leaf[31] = (const char*)d_in[src++];

    const float* u    = (const float*)leaf[0];
    const float* nu   = (const float*)leaf[1];
    const float* fc0w = (const float*)leaf[2];
    const float* fc0b = (const float*)leaf[3];
    const float* convw[4], *convb[4];
    for (int i = 0; i < 4; ++i) { convw[i] = (const float*)leaf[20 + i];
                                  convb[i] = (const float*)leaf[24 + i]; }
    const float* fc1w = (const float*)leaf[28];
    const float* fc1b = (const float*)leaf[29];
    const float* fc2w = (const float*)leaf[30];
    const float* fc2b = (const float*)leaf[31];

    // scratch: x | Bh | O | SP.  Fallback: Bh,SP in d_out (dead before
    // k_ptout writes it); O must stay in ws (live during k_ptout).
    const size_t szX = 67108864, szB = 1048576, szO = 131072, szSP = 524288;
    char* ws = (char*)d_ws;
    float* xbuf = (float*)ws;
    float2 *Bbuf, *Obuf, *SP;
    if (ws_size >= szX + szB + szO + szSP) {
        Bbuf = (float2*)(ws + szX);
        Obuf = (float2*)(ws + szX + szB);
        SP   = (float2*)(ws + szX + szB + szO);
    } else {
        Obuf = (float2*)(ws + szX);
        Bbuf = (float2*)d_out;
        SP   = (float2*)((char*)d_out + szB);
    }

    const float2* specw[16];
    if (spec_split) {
        PackPtrs pp;
        for (int i = 0; i < 16; ++i) {
            pp.re[i] = (const float*)spec_re[i];
            pp.im[i] = (const float*)spec_im[i];
            specw[i] = SP + (size_t)i * 4096;
        }
        hipLaunchKernelGGL(k_pack_all, dim3(256), dim3(256), 0, stream, pp, SP);
    } else {
        for (int i = 0; i < 16; ++i) specw[i] = (const float2*)leaf[4 + i];
    }
    float* outp = (float*)d_out;

    hipLaunchKernelGGL(k_liftA2, dim3(512), dim3(1024), 0, stream,
                       u, fc0w, fc0b, xbuf, Bbuf);
    for (int L = 0; L < 4; ++L) {
        hipLaunchKernelGGL(k_fDmix, dim3(64), dim3(1024), 0, stream,
                           Bbuf, specw[L*4+0], specw[L*4+1], specw[L*4+2], specw[L*4+3], Obuf);
        if (L < 3) {
            hipLaunchKernelGGL(k_ptA2, dim3(512), dim3(1024), 0, stream,
                               xbuf, Obuf, convw[L], convb[L], Bbuf);
        } else {
            hipLaunchKernelGGL(k_ptout, dim3(2048), dim3(256), 0, stream,
                               xbuf, Obuf, convw[3], convb[3], u, nu,
                               fc1w, fc1b, fc2w, fc2b, outp);
        }
    }
}

// Round 3
// 305.543 us; speedup vs baseline: 2.3436x; 2.3436x over previous
//
#include <hip/hip_runtime.h>

// FNO3d forward, MI355X. Round 9:
//  - R8 structure kept (k_fH deleted; W-DFT tail -> LDS; in-block ky-DFT;
//    k_fDmix 4-way dx split). R8's regression was __launch_bounds__(1024,8):
//    it capped VGPRs at 64, compiler chose 32 -> spilled xv[8]+twiddles to
//    scratch -> 750MB HBM traffic/dispatch, 180us. Fix: (1024,4) = 1 block/CU
//    minimum -> 128 VGPR budget, no spill.
//
// Layouts:
//   x  : float [B=8][C=8][64][64][64]          (67,108,864 B)
//   Bh : float2[8][8][dx=64][ky=8][kz=4]      ( 1,048,576 B)
//   O  : float2[8][8][kx=8][ky=8][kz=4]      (   131,072 B)

#define TWO_PI_OVER_64 0.09817477042468103

__device__ __forceinline__ float gelu_fast(float x) {
    float x2 = x * x;
    float p  = x * (1.0f + 0.044715f * x2);
    float e  = __builtin_amdgcn_exp2f(-2.3022083f * p);
    return x * __builtin_amdgcn_rcpf(1.0f + e);
}

#define BUILD_TW() \
    __shared__ float twc[64], tws[64]; \
    if (threadIdx.x < 64) { \
        double a_ = TWO_PI_OVER_64 * (double)threadIdx.x; \
        twc[threadIdx.x] = (float)cos(a_); tws[threadIdx.x] = (float)sin(a_); \
    }

// DPP row_ror rotation-add: after steps 1,2,4,8 every lane of each 16-lane
// row holds the row sum. VALU-only.
#define ROR_STEP(x, CTRL) \
    x += __int_as_float(__builtin_amdgcn_update_dpp( \
            0, __float_as_int(x), CTRL, 0xF, 0xF, true))

__device__ __forceinline__ float red16_ror(float x) {
    ROR_STEP(x, 0x121);   // row_ror:1
    ROR_STEP(x, 0x122);   // row_ror:2
    ROR_STEP(x, 0x124);   // row_ror:4
    ROR_STEP(x, 0x128);   // row_ror:8
    return x;
}

// 4-lane (quad) reduce: quad_perm [1,0,3,2] then [2,3,0,1].
__device__ __forceinline__ float red4_quad(float x) {
    x += __int_as_float(__builtin_amdgcn_update_dpp(
            0, __float_as_int(x), 0xB1, 0xF, 0xF, true));
    x += __int_as_float(__builtin_amdgcn_update_dpp(
            0, __float_as_int(x), 0x4E, 0xF, 0xF, true));
    return x;
}

// A-tail (LDS dest): partial W-DFT over 4 w-points, DPP reduce across the 16
// wq-lanes, predicated float4 store into As row (wq=0 -> kz0/1, wq=1 -> kz2/3).
__device__ __forceinline__ void a_tail_lds(
    const float v[4], const float c1[4], const float s1[4],
    const float c2[4], const float s2[4], const float c3[4], const float s3[4],
    int wq, float2* __restrict__ AsRow)
{
    float p0  = v[0] + v[1] + v[2] + v[3];
    float ar1 = v[0]*c1[0] + v[1]*c1[1] + v[2]*c1[2] + v[3]*c1[3];
    float ai1 = -(v[0]*s1[0] + v[1]*s1[1] + v[2]*s1[2] + v[3]*s1[3]);
    float ar2 = v[0]*c2[0] + v[1]*c2[1] + v[2]*c2[2] + v[3]*c2[3];
    float ai2 = -(v[0]*s2[0] + v[1]*s2[1] + v[2]*s2[2] + v[3]*s2[3]);
    float ar3 = v[0]*c3[0] + v[1]*c3[1] + v[2]*c3[2] + v[3]*c3[3];
    float ai3 = -(v[0]*s3[0] + v[1]*s3[1] + v[2]*s3[2] + v[3]*s3[3]);
    p0  = red16_ror(p0);
    ar1 = red16_ror(ar1);  ai1 = red16_ror(ai1);
    ar2 = red16_ror(ar2);  ai2 = red16_ror(ai2);
    ar3 = red16_ror(ar3);  ai3 = red16_ror(ai3);
    if (wq < 2) {
        float4 av;
        av.x = (wq == 0) ? p0   : ar2;
        av.y = (wq == 0) ? 0.f  : ai2;
        av.z = (wq == 0) ? ar1  : ar3;
        av.w = (wq == 0) ? ai1  : ai3;
        *((float4*)AsRow + wq) = av;
    }
}

// In-block ky-DFT over the LDS A-plane -> Bh[b,c,dx,ky,kz].
// 1024 threads: out = t>>2 (c,ky,kz), q = t&3 sums dy = q,q+4,... (16 terms,
// stride-4 keeps LDS banks spread), quad reduce, lane q==0 writes.
__device__ __forceinline__ void ky_dft_store(
    const float2* __restrict__ As, const float* __restrict__ twc,
    const float* __restrict__ tws, int t, int b, int dx,
    float2* __restrict__ Bh)
{
    const int out = t >> 2, q = t & 3;
    const int c = out >> 5, ky = (out >> 2) & 7, kz = out & 3;
    const int kyv = ky < 4 ? ky : ky + 56;
    float re = 0.f, im = 0.f;
    int ti = (kyv * q) & 63;
    const int step = (kyv * 4) & 63;
    #pragma unroll 4
    for (int i = 0; i < 16; ++i) {
        int dy = q + i * 4;
        float2 a = As[(c * 64 + dy) * 4 + kz];
        float cc = twc[ti], ss = tws[ti];
        re += a.x * cc + a.y * ss;   // * e^{-i phi}
        im += a.y * cc - a.x * ss;
        ti = (ti + step) & 63;
    }
    re = red4_quad(re);
    im = red4_quad(im);
    if (q == 0)
        Bh[(size_t)(b * 8 + c) * 2048 + dx * 32 + ky * 4 + kz] =
            make_float2(re, im);
}

// ---------------------------------------------------------------------------
// Lift (3->8 ch) + forward W-DFT (DPP tail, LDS) + in-block ky-DFT -> Bh.
// grid 512 = b(8)*dx(64); block 1024 (dyl = t>>4 in 0..63, wq = t&15).
// ---------------------------------------------------------------------------
__global__ __launch_bounds__(1024, 4) void k_liftA2(
    const float* __restrict__ u, const float* __restrict__ fc0w,
    const float* __restrict__ fc0b, float* __restrict__ x,
    float2* __restrict__ Bh)
{
    BUILD_TW();
    __shared__ float2 As[8 * 64 * 4];   // [c][dy][kz], 16KB
    const int t = threadIdx.x, bid = blockIdx.x;
    const int b = bid >> 6, dx = bid & 63;
    const int dyl = t >> 4, wq = t & 15;
    const size_t sp = (size_t)dx * 4096 + (size_t)dyl * 64 + wq * 4;
    float uin[3][4];
    #pragma unroll
    for (int c = 0; c < 3; ++c) {
        float4 v = *(const float4*)&u[(size_t)(b * 3 + c) * 262144 + sp];
        uin[c][0] = v.x; uin[c][1] = v.y; uin[c][2] = v.z; uin[c][3] = v.w;
    }
    __syncthreads();
    float c1[4], s1[4], c2[4], s2[4], c3[4], s3[4];
    #pragma unroll
    for (int j = 0; j < 4; ++j) {
        int w = wq * 4 + j;
        c1[j] = twc[w];             s1[j] = tws[w];
        c2[j] = twc[(2 * w) & 63];  s2[j] = tws[(2 * w) & 63];
        c3[j] = twc[(3 * w) & 63];  s3[j] = tws[(3 * w) & 63];
    }
    #pragma unroll
    for (int o = 0; o < 8; ++o) {
        float w0 = fc0w[o * 3 + 0], w1 = fc0w[o * 3 + 1], w2 = fc0w[o * 3 + 2];
        float bb = fc0b[o];
        float v[4];
        #pragma unroll
        for (int j = 0; j < 4; ++j)
            v[j] = bb + uin[0][j] * w0 + uin[1][j] * w1 + uin[2][j] * w2;
        *(float4*)&x[(size_t)(b * 8 + o) * 262144 + sp] =
            make_float4(v[0], v[1], v[2], v[3]);
        a_tail_lds(v, c1, s1, c2, s2, c3, s3, wq, &As[(o * 64 + dyl) * 4]);
    }
    __syncthreads();
    ky_dft_store(As, twc, tws, t, b, dx, Bh);
}

// ---------------------------------------------------------------------------
// D-axis DFT (dx-sum split 4-way, quad reduce) + spectral mix.
// grid 64 = b(8)*kx(8); block 1024.
// ---------------------------------------------------------------------------
__global__ __launch_bounds__(1024) void k_fDmix(
    const float2* __restrict__ Bh,
    const float2* __restrict__ w1, const float2* __restrict__ w2,
    const float2* __restrict__ w3, const float2* __restrict__ w4,
    float2* __restrict__ O)
{
    BUILD_TW();
    __shared__ float2 Cs[256];   // [c][ky][kz] = c*32 + ky*4 + kz
    const int t = threadIdx.x, bid = blockIdx.x;
    const int b = bid >> 3, kx = bid & 7;
    const int kxv = kx < 4 ? kx : kx + 56;
    __syncthreads();
    {
        const int out = t >> 2, q = t & 3;
        const int kz = out & 3, ky = (out >> 2) & 7, c = out >> 5;
        const float2* Bp = Bh + (size_t)(b * 8 + c) * 2048 + ky * 4 + kz;
        float re = 0.f, im = 0.f;
        int ti = (kxv * q) & 63;
        const int step = (kxv * 4) & 63;
        #pragma unroll 4
        for (int i = 0; i < 16; ++i) {
            float2 v = Bp[(q + i * 4) * 32];
            float cc = twc[ti], ss = tws[ti];
            re += v.x * cc + v.y * ss;
            im += v.y * cc - v.x * ss;
            ti = (ti + step) & 63;
        }
        re = red4_quad(re);
        im = red4_quad(im);
        if (q == 0) Cs[out] = make_float2(re, im);
    }
    __syncthreads();
    if (t < 256) {
        int kz = t & 3, ky = (t >> 2) & 7, o = t >> 5;
        const float2* wsel = (kx < 4) ? ((ky < 4) ? w1 : w3) : ((ky < 4) ? w2 : w4);
        int kxw = kx & 3, kyw = ky & 3;
        float re = 0.f, im = 0.f;
        #pragma unroll
        for (int i = 0; i < 8; ++i) {
            float2 cv = Cs[i * 32 + ky * 4 + kz];
            float2 wv = wsel[(((size_t)(i * 8 + o) * 4 + kxw) * 4 + kyw) * 4 + kz];
            re += cv.x * wv.x - cv.y * wv.y;
            im += cv.x * wv.y + cv.y * wv.x;
        }
        O[(((size_t)(b * 8 + o) * 8 + kx) * 8 + ky) * 4 + kz] = make_float2(re, im);
    }
}

// ---------------------------------------------------------------------------
// Inverse D/H DFT in LDS + irfftW + conv + gelu + x in place + W-DFT tail to
// LDS + in-block ky-DFT -> Bh. grid 512 = b(8)*dx(64); block 1024.
// ---------------------------------------------------------------------------
__global__ __launch_bounds__(1024, 4) void k_ptA2(
    float* __restrict__ x, const float2* __restrict__ O,
    const float* __restrict__ cw, const float* __restrict__ cb,
    float2* __restrict__ Bh)
{
    BUILD_TW();
    __shared__ float2 Ps[256];          // [o][ky][kz]
    __shared__ float2 Qs[8 * 64 * 4];   // [o][dy][kz], 16KB
    __shared__ float2 As[8 * 64 * 4];   // [o][dy][kz], 16KB
    const int t = threadIdx.x, bid = blockIdx.x;
    const int b = bid >> 6, dx = bid & 63;
    const int dyl = t >> 4, wq = t & 15;
    const size_t sp = (size_t)dx * 4096 + (size_t)dyl * 64 + wq * 4;
    // ---- prefetch: all global loads issued before any barrier ----
    float4 xv[8];
    #pragma unroll
    for (int c = 0; c < 8; ++c)
        xv[c] = *(const float4*)&x[(size_t)(b * 8 + c) * 262144 + sp];
    float2 ov[8];
    if (t < 256) {
        const int pkz = t & 3, pky = (t >> 2) & 7, po = t >> 5;
        #pragma unroll
        for (int kxi = 0; kxi < 8; ++kxi)
            ov[kxi] = O[(((size_t)(b * 8 + po) * 8 + kxi) * 8 + pky) * 4 + pkz];
    }
    __syncthreads();
    if (t < 256) {   // Ps: inverse D-DFT of O at this dx
        float re = 0.f, im = 0.f;
        #pragma unroll
        for (int kxi = 0; kxi < 8; ++kxi) {
            int kxv = kxi < 4 ? kxi : kxi + 56;
            int ti = (kxv * dx) & 63;
            float cc = twc[ti], ss = tws[ti];
            re += ov[kxi].x * cc - ov[kxi].y * ss;   // * e^{+i phi}
            im += ov[kxi].y * cc + ov[kxi].x * ss;
        }
        Ps[t] = make_float2(re, im);
    }
    __syncthreads();
    #pragma unroll
    for (int it = t; it < 2048; it += 1024) {   // Qs: inverse H-DFT
        int kz = it & 3, dy = (it >> 2) & 63, o = it >> 8;
        float re = 0.f, im = 0.f;
        #pragma unroll
        for (int kyi = 0; kyi < 8; ++kyi) {
            int kyv = kyi < 4 ? kyi : kyi + 56;
            int ti = (kyv * dy) & 63;
            float2 v = Ps[(o * 8 + kyi) * 4 + kz];
            float cc = twc[ti], ss = tws[ti];
            re += v.x * cc - v.y * ss;
            im += v.y * cc + v.x * ss;
        }
        Qs[(o * 64 + dy) * 4 + kz] = make_float2(re, im);
    }
    __syncthreads();
    float c1[4], s1[4], c2[4], s2[4], c3[4], s3[4];
    #pragma unroll
    for (int j = 0; j < 4; ++j) {
        int w = wq * 4 + j;
        c1[j] = twc[w];             s1[j] = tws[w];
        c2[j] = twc[(2 * w) & 63];  s2[j] = tws[(2 * w) & 63];
        c3[j] = twc[(3 * w) & 63];  s3[j] = tws[(3 * w) & 63];
    }
    const float invN3 = 1.0f / 262144.0f;
    #pragma unroll
    for (int o = 0; o < 8; ++o) {
        float4 qa = *(const float4*)&Qs[(o * 64 + dyl) * 4];      // q0,q1
        float4 qb = *(const float4*)&Qs[(o * 64 + dyl) * 4 + 2];  // q2,q3
        float outj[4];
        #pragma unroll
        for (int j = 0; j < 4; ++j) {
            float x1 = qa.x + 2.f * (qa.z * c1[j] - qa.w * s1[j]
                                   + qb.x * c2[j] - qb.y * s2[j]
                                   + qb.z * c3[j] - qb.w * s3[j]);
            x1 *= invN3;
            float x2 = cb[o];
            #pragma unroll
            for (int c = 0; c < 8; ++c) {
                const float* xc = &xv[c].x;
                x2 += cw[o * 8 + c] * xc[j];
            }
            outj[j] = gelu_fast(x1 + x2);
        }
        *(float4*)&x[(size_t)(b * 8 + o) * 262144 + sp] =
            make_float4(outj[0], outj[1], outj[2], outj[3]);
        a_tail_lds(outj, c1, s1, c2, s2, c3, s3, wq, &As[(o * 64 + dyl) * 4]);
    }
    __syncthreads();
    ky_dft_store(As, twc, tws, t, b, dx, Bh);
}

// ---------------------------------------------------------------------------
// Layer 3: inverse DFT + conv (no gelu) -> fc1+gelu+fc2, + hard core u*nu.
// Writes d_out only; x/u prefetched at top. grid 2048; block 256.
// ---------------------------------------------------------------------------
__global__ __launch_bounds__(256, 4) void k_ptout(
    const float* __restrict__ x, const float2* __restrict__ O,
    const float* __restrict__ cw, const float* __restrict__ cb,
    const float* __restrict__ u, const float* __restrict__ nu,
    const float* __restrict__ fc1w, const float* __restrict__ fc1b,
    const float* __restrict__ fc2w, const float* __restrict__ fc2b,
    float* __restrict__ out)
{
    BUILD_TW();
    __shared__ float2 Ps[256];
    __shared__ float2 Qs[8 * 16 * 4];
    const int t = threadIdx.x, bid = blockIdx.x;
    const int b = bid >> 8, dx = (bid >> 2) & 63, dy0 = (bid & 3) * 16;
    const int dyl = t >> 4, wq = t & 15;
    const size_t sp = (size_t)dx * 4096 + (size_t)(dy0 + dyl) * 64 + wq * 4;
    float4 xv[8];
    #pragma unroll
    for (int c = 0; c < 8; ++c)
        xv[c] = *(const float4*)&x[(size_t)(b * 8 + c) * 262144 + sp];
    float4 uv[3];
    #pragma unroll
    for (int c = 0; c < 3; ++c)
        uv[c] = *(const float4*)&u[(size_t)(b * 3 + c) * 262144 + sp];
    const int pkz = t & 3, pky = (t >> 2) & 7, po = t >> 5;
    float2 ovv[8];
    #pragma unroll
    for (int kxi = 0; kxi < 8; ++kxi)
        ovv[kxi] = O[(((size_t)(b * 8 + po) * 8 + kxi) * 8 + pky) * 4 + pkz];
    __syncthreads();
    {
        float re = 0.f, im = 0.f;
        #pragma unroll
        for (int kxi = 0; kxi < 8; ++kxi) {
            int kxv = kxi < 4 ? kxi : kxi + 56;
            int ti = (kxv * dx) & 63;
            float cc = twc[ti], ss = tws[ti];
            re += ovv[kxi].x * cc - ovv[kxi].y * ss;
            im += ovv[kxi].y * cc + ovv[kxi].x * ss;
        }
        Ps[t] = make_float2(re, im);
    }
    __syncthreads();
    for (int it = t; it < 512; it += 256) {
        int kz = it & 3, qdyl = (it >> 2) & 15, o = it >> 6;
        int dy = dy0 + qdyl;
        float re = 0.f, im = 0.f;
        #pragma unroll
        for (int kyi = 0; kyi < 8; ++kyi) {
            int kyv = kyi < 4 ? kyi : kyi + 56;
            int ti = (kyv * dy) & 63;
            float2 v = Ps[(o * 8 + kyi) * 4 + kz];
            float cc = twc[ti], ss = tws[ti];
            re += v.x * cc - v.y * ss;
            im += v.y * cc + v.x * ss;
        }
        Qs[(o * 16 + qdyl) * 4 + kz] = make_float2(re, im);
    }
    __syncthreads();
    float c1[4], s1[4], c2[4], s2[4], c3[4], s3[4];
    #pragma unroll
    for (int j = 0; j < 4; ++j) {
        int w = wq * 4 + j;
        c1[j] = twc[w];             s1[j] = tws[w];
        c2[j] = twc[(2 * w) & 63];  s2[j] = tws[(2 * w) & 63];
        c3[j] = twc[(3 * w) & 63];  s3[j] = tws[(3 * w) & 63];
    }
    const float invN3 = 1.0f / 262144.0f;
    float vv[8][4];   // layer-3 activations (no gelu)
    #pragma unroll
    for (int o = 0; o < 8; ++o) {
        float4 qa = *(const float4*)&Qs[(o * 16 + dyl) * 4];
        float4 qb = *(const float4*)&Qs[(o * 16 + dyl) * 4 + 2];
        #pragma unroll
        for (int j = 0; j < 4; ++j) {
            float x1 = qa.x + 2.f * (qa.z * c1[j] - qa.w * s1[j]
                                   + qb.x * c2[j] - qb.y * s2[j]
                                   + qb.z * c3[j] - qb.w * s3[j]);
            x1 *= invN3;
            float x2 = cb[o];
            #pragma unroll
            for (int c = 0; c < 8; ++c) {
                const float* xc = &xv[c].x;
                x2 += cw[o * 8 + c] * xc[j];
            }
            vv[o][j] = x1 + x2;
        }
    }
    float so[6][4];
    #pragma unroll
    for (int c6 = 0; c6 < 6; ++c6)
        #pragma unroll
        for (int j = 0; j < 4; ++j) so[c6][j] = fc2b[c6];
    #pragma unroll 4
    for (int h = 0; h < 32; ++h) {
        float wr[8];
        #pragma unroll
        for (int c = 0; c < 8; ++c) wr[c] = fc1w[h * 8 + c];   // uniform -> SGPR
        const float hb = fc1b[h];
        float w2r[6];
        #pragma unroll
        for (int c6 = 0; c6 < 6; ++c6) w2r[c6] = fc2w[c6 * 32 + h];
        #pragma unroll
        for (int j = 0; j < 4; ++j) {
            float a = hb;
            #pragma unroll
            for (int c = 0; c < 8; ++c) a += vv[c][j] * wr[c];
            float g = gelu_fast(a);
            #pragma unroll
            for (int c6 = 0; c6 < 6; ++c6) so[c6][j] += g * w2r[c6];
        }
    }
    const float nuv = nu[0];
    #pragma unroll
    for (int c6 = 0; c6 < 6; ++c6) {
        float4 res;
        float* rp = &res.x;
        if (c6 < 3) {
            const float* up = &uv[c6].x;
            #pragma unroll
            for (int j = 0; j < 4; ++j) rp[j] = 0.3f * so[c6][j] + up[j] * nuv;
        } else {
            #pragma unroll
            for (int j = 0; j < 4; ++j) rp[j] = 0.3f * so[c6][j];
        }
        *(float4*)&out[(size_t)(b * 6 + c6) * 262144 + sp] = res;
    }
}

// pack split re/im spectral leaves into interleaved float2, ALL 16 weights
// in one dispatch (pointers passed by value).
struct PackPtrs { const float* re[16]; const float* im[16]; };

__global__ __launch_bounds__(256) void k_pack_all(PackPtrs p, float2* __restrict__ dst)
{
    int i = blockIdx.x * 256 + threadIdx.x;   // 65536 = 16 * 4096
    int w = i >> 12, idx = i & 4095;
    dst[i] = make_float2(p.re[w][idx], p.im[w][idx]);
}

// ---------------------------------------------------------------------------
extern "C" void kernel_launch(void* const* d_in, const int* in_sizes, int n_in,
                              void* d_out, int out_size, void* d_ws, size_t ws_size,
                              hipStream_t stream)
{
    (void)out_size;
    const char* leaf[32];
    bool spec_split = false;
    const char* spec_re[16]; const char* spec_im[16];
    int src = 0;
    leaf[0] = (const char*)d_in[src++];
    leaf[1] = (const char*)d_in[src++];
    leaf[2] = (const char*)d_in[src++];
    leaf[3] = (const char*)d_in[src++];
    {
        int s = (src < n_in) ? in_sizes[src] : 4096;
        if (n_in >= 48 && s == 4096) {
            spec_split = true;
            for (int i = 0; i < 16; ++i) {
                spec_re[i] = (const char*)d_in[src++];
                spec_im[i] = (const char*)d_in[src++];
            }
        } else {
            int per;
            if (s == 4096 || s == 8192) per = 1;
            else if (s == 16384 || s == 32768) per = 4;
            else per = 16;
            for (int i = 0; i < 16; i += per) {
                const char* base = (const char*)d_in[src++];
                for (int j = 0; j < per; ++j) leaf[4 + i + j] = base + (size_t)j * 4096 * 8;
            }
        }
    }
    {
        int s = (src < n_in) ? in_sizes[src] : 64;
        if (s == 64) { for (int i = 0; i < 4; ++i) leaf[20 + i] = (const char*)d_in[src++]; }
        else { const char* base = (const char*)d_in[src++];
               for (int i = 0; i < 4; ++i) leaf[20 + i] = base + (size_t)i * 64 * 4; }
    }
    {
        int s = (src < n_in) ? in_sizes[src] : 8;
        if (s == 8) { for (int i = 0; i < 4; ++i) leaf[24 + i] = (const char*)d_in[src++]; }
        else { const char* base = (const char*)d_in[src++];
               for (int i = 0; i < 4; ++i) leaf[24 + i] = base + (size_t)i * 8 * 4; }
    }
    leaf[28] = (const char*)d_in[src++];
    leaf[29] = (const char*)d_in[src++];
    leaf[30] = (const char*)d_in[src++];
    leaf[31] = (const char*)d_in[src++];

    const float* u    = (const float*)leaf[0];
    const float* nu   = (const float*)leaf[1];
    const float* fc0w = (const float*)leaf[2];
    const float* fc0b = (const float*)leaf[3];
    const float* convw[4], *convb[4];
    for (int i = 0; i < 4; ++i) { convw[i] = (const float*)leaf[20 + i];
                                  convb[i] = (const float*)leaf[24 + i]; }
    const float* fc1w = (const float*)leaf[28];
    const float* fc1b = (const float*)leaf[29];
    const float* fc2w = (const float*)leaf[30];
    const float* fc2b = (const float*)leaf[31];

    // scratch: x | Bh | O | SP.  Fallback: Bh,SP in d_out (dead before
    // k_ptout writes it); O must stay in ws (live during k_ptout).
    const size_t szX = 67108864, szB = 1048576, szO = 131072, szSP = 524288;
    char* ws = (char*)d_ws;
    float* xbuf = (float*)ws;
    float2 *Bbuf, *Obuf, *SP;
    if (ws_size >= szX + szB + szO + szSP) {
        Bbuf = (float2*)(ws + szX);
        Obuf = (float2*)(ws + szX + szB);
        SP   = (float2*)(ws + szX + szB + szO);
    } else {
        Obuf = (float2*)(ws + szX);
        Bbuf = (float2*)d_out;
        SP   = (float2*)((char*)d_out + szB);
    }

    const float2* specw[16];
    if (spec_split) {
        PackPtrs pp;
        for (int i = 0; i < 16; ++i) {
            pp.re[i] = (const float*)spec_re[i];
            pp.im[i] = (const float*)spec_im[i];
            specw[i] = SP + (size_t)i * 4096;
        }
        hipLaunchKernelGGL(k_pack_all, dim3(256), dim3(256), 0, stream, pp, SP);
    } else {
        for (int i = 0; i < 16; ++i) specw[i] = (const float2*)leaf[4 + i];
    }
    float* outp = (float*)d_out;

    hipLaunchKernelGGL(k_liftA2, dim3(512), dim3(1024), 0, stream,
                       u, fc0w, fc0b, xbuf, Bbuf);
    for (int L = 0; L < 4; ++L) {
        hipLaunchKernelGGL(k_fDmix, dim3(64), dim3(1024), 0, stream,
                           Bbuf, specw[L*4+0], specw[L*4+1], specw[L*4+2], specw[L*4+3], Obuf);
        if (L < 3) {
            hipLaunchKernelGGL(k_ptA2, dim3(512), dim3(1024), 0, stream,
                               xbuf, Obuf, convw[L], convb[L], Bbuf);
        } else {
            hipLaunchKernelGGL(k_ptout, dim3(2048), dim3(256), 0, stream,
                               xbuf, Obuf, convw[3], convb[3], u, nu,
                               fc1w, fc1b, fc2w, fc2b, outp);
        }
    }
}

// Round 4
// 294.846 us; speedup vs baseline: 2.4287x; 1.0363x over previous
//
#include <hip/hip_runtime.h>

// FNO3d forward, MI355X. Round 10:
//  - Revert to R7 structure (256-thread ptA/liftA + separate k_fH): R8/R9's
//    1024-thread fusion ran 1 block/CU (VGPR ~100 forbids 2) -> barrier
//    stalls ate the fusion gains (53us/kernel vs 48+7 shared).
//  - k_fH rewritten: LDS-staged. Each block stages a contiguous 16KB 8-dx
//    slab of A via one coalesced float4/thread, then ky-DFT from LDS with
//    dy-sum split 4-way (quad reduce). 1024t, ~24 VGPR -> 2 blocks/CU,
//    16-iter loop instead of 64 uncoalesced global reads (8x re-read).
//  - k_fDmix kept as R9's 1024-thread 4-way-split version (validated).
//
// Layouts:
//   x  : float [B=8][C=8][64][64][64]          (67,108,864 B)
//   A  : float2[8][8][dx=64][dy=64][kz=4]      ( 8,388,608 B)
//   Bh : float2[8][8][dx=64][ky=8][kz=4]       ( 1,048,576 B)
//   O  : float2[8][8][kx=8][ky=8][kz=4]        (   131,072 B)

#define TWO_PI_OVER_64 0.09817477042468103

__device__ __forceinline__ float gelu_fast(float x) {
    float x2 = x * x;
    float p  = x * (1.0f + 0.044715f * x2);
    float e  = __builtin_amdgcn_exp2f(-2.3022083f * p);
    return x * __builtin_amdgcn_rcpf(1.0f + e);
}

#define BUILD_TW() \
    __shared__ float twc[64], tws[64]; \
    if (threadIdx.x < 64) { \
        double a_ = TWO_PI_OVER_64 * (double)threadIdx.x; \
        twc[threadIdx.x] = (float)cos(a_); tws[threadIdx.x] = (float)sin(a_); \
    }

// DPP row_ror rotation-add: after steps 1,2,4,8 every lane of each 16-lane
// row holds the row sum. VALU-only (no ds_bpermute / LDS pipe).
#define ROR_STEP(x, CTRL) \
    x += __int_as_float(__builtin_amdgcn_update_dpp( \
            0, __float_as_int(x), CTRL, 0xF, 0xF, true))

__device__ __forceinline__ float red16_ror(float x) {
    ROR_STEP(x, 0x121);   // row_ror:1
    ROR_STEP(x, 0x122);   // row_ror:2
    ROR_STEP(x, 0x124);   // row_ror:4
    ROR_STEP(x, 0x128);   // row_ror:8
    return x;
}

// 4-lane (quad) reduce: quad_perm [1,0,3,2] then [2,3,0,1].
__device__ __forceinline__ float red4_quad(float x) {
    x += __int_as_float(__builtin_amdgcn_update_dpp(
            0, __float_as_int(x), 0xB1, 0xF, 0xF, true));
    x += __int_as_float(__builtin_amdgcn_update_dpp(
            0, __float_as_int(x), 0x4E, 0xF, 0xF, true));
    return x;
}

// A-tail: partial W-DFT over this lane's 4 w-points, DPP reduce across the 16
// wq-lanes, predicated float4 store (lane wq=0 -> kz0/1, wq=1 -> kz2/3).
__device__ __forceinline__ void a_tail_store(
    const float v[4], const float c1[4], const float s1[4],
    const float c2[4], const float s2[4], const float c3[4], const float s3[4],
    int wq, float2* __restrict__ Arow)
{
    float p0  = v[0] + v[1] + v[2] + v[3];
    float ar1 = v[0]*c1[0] + v[1]*c1[1] + v[2]*c1[2] + v[3]*c1[3];
    float ai1 = -(v[0]*s1[0] + v[1]*s1[1] + v[2]*s1[2] + v[3]*s1[3]);
    float ar2 = v[0]*c2[0] + v[1]*c2[1] + v[2]*c2[2] + v[3]*c2[3];
    float ai2 = -(v[0]*s2[0] + v[1]*s2[1] + v[2]*s2[2] + v[3]*s2[3]);
    float ar3 = v[0]*c3[0] + v[1]*c3[1] + v[2]*c3[2] + v[3]*c3[3];
    float ai3 = -(v[0]*s3[0] + v[1]*s3[1] + v[2]*s3[2] + v[3]*s3[3]);
    p0  = red16_ror(p0);
    ar1 = red16_ror(ar1);  ai1 = red16_ror(ai1);
    ar2 = red16_ror(ar2);  ai2 = red16_ror(ai2);
    ar3 = red16_ror(ar3);  ai3 = red16_ror(ai3);
    if (wq < 2) {
        float4 av;
        av.x = (wq == 0) ? p0   : ar2;
        av.y = (wq == 0) ? 0.f  : ai2;
        av.z = (wq == 0) ? ar1  : ar3;
        av.w = (wq == 0) ? ai1  : ai3;
        *((float4*)Arow + wq) = av;
    }
}

// ---------------------------------------------------------------------------
// Lift (3->8 ch) + forward W-DFT (DPP tail).
// grid 2048 = b(8)*dx(64)*dyq(4); block 256 (dyl = t>>4, wq = t&15).
// ---------------------------------------------------------------------------
__global__ __launch_bounds__(256) void k_liftA(
    const float* __restrict__ u, const float* __restrict__ fc0w,
    const float* __restrict__ fc0b, float* __restrict__ x,
    float2* __restrict__ A)
{
    BUILD_TW();
    const int t = threadIdx.x, bid = blockIdx.x;
    const int b = bid >> 8, dx = (bid >> 2) & 63, dy0 = (bid & 3) * 16;
    const int dyl = t >> 4, wq = t & 15;
    const size_t sp = (size_t)dx * 4096 + (size_t)(dy0 + dyl) * 64 + wq * 4;
    float uin[3][4];
    #pragma unroll
    for (int c = 0; c < 3; ++c) {
        float4 v = *(const float4*)&u[(size_t)(b * 3 + c) * 262144 + sp];
        uin[c][0] = v.x; uin[c][1] = v.y; uin[c][2] = v.z; uin[c][3] = v.w;
    }
    __syncthreads();
    float c1[4], s1[4], c2[4], s2[4], c3[4], s3[4];
    #pragma unroll
    for (int j = 0; j < 4; ++j) {
        int w = wq * 4 + j;
        c1[j] = twc[w];             s1[j] = tws[w];
        c2[j] = twc[(2 * w) & 63];  s2[j] = tws[(2 * w) & 63];
        c3[j] = twc[(3 * w) & 63];  s3[j] = tws[(3 * w) & 63];
    }
    #pragma unroll
    for (int o = 0; o < 8; ++o) {
        float w0 = fc0w[o * 3 + 0], w1 = fc0w[o * 3 + 1], w2 = fc0w[o * 3 + 2];
        float bb = fc0b[o];
        float v[4];
        #pragma unroll
        for (int j = 0; j < 4; ++j)
            v[j] = bb + uin[0][j] * w0 + uin[1][j] * w1 + uin[2][j] * w2;
        *(float4*)&x[(size_t)(b * 8 + o) * 262144 + sp] =
            make_float4(v[0], v[1], v[2], v[3]);
        a_tail_store(v, c1, s1, c2, s2, c3, s3, wq,
                     A + ((size_t)(b * 8 + o) * 4096 + dx * 64 + dy0 + dyl) * 4);
    }
}

// ---------------------------------------------------------------------------
// H-axis DFT, LDS-staged: A[b,c,dx,dy,kz] -> Bh[b,c,dx,ky,kz].
// grid 512 = b(8)*c(8)*dxg(8); block 1024. Each block stages a contiguous
// 16KB slab (8 dx rows) of A with one coalesced float4/thread, then computes
// 256 outputs with the dy-sum split 4-way across lanes (quad reduce).
// ---------------------------------------------------------------------------
__global__ __launch_bounds__(1024, 4) void k_fH(const float2* __restrict__ A,
                                                float2* __restrict__ Bh)
{
    BUILD_TW();
    __shared__ float2 As[2048];   // [dxl(8)][dy(64)][kz(4)], 16KB
    const int t = threadIdx.x, bid = blockIdx.x;
    const int b = bid >> 6, c = (bid >> 3) & 7, dxg = bid & 7;
    const size_t base = (size_t)(b * 8 + c) * 16384 + (size_t)dxg * 2048;
    ((float4*)As)[t] = ((const float4*)(A + base))[t];   // 1024 x 16B coalesced
    __syncthreads();
    const int out = t >> 2, q = t & 3;
    const int kz = out & 3, ky = (out >> 2) & 7, dxl = out >> 5;
    const int kyv = ky < 4 ? ky : ky + 56;
    float re = 0.f, im = 0.f;
    int ti = (kyv * q) & 63;
    const int step = (kyv * 4) & 63;
    #pragma unroll 4
    for (int i = 0; i < 16; ++i) {
        int dy = q + i * 4;
        float2 a = As[dxl * 256 + dy * 4 + kz];
        float cc = twc[ti], ss = tws[ti];
        re += a.x * cc + a.y * ss;   // * e^{-i phi}
        im += a.y * cc - a.x * ss;
        ti = (ti + step) & 63;
    }
    re = red4_quad(re);
    im = red4_quad(im);
    if (q == 0)
        Bh[(size_t)(b * 8 + c) * 2048 + (dxg * 8 + dxl) * 32 + ky * 4 + kz] =
            make_float2(re, im);
}

// ---------------------------------------------------------------------------
// D-axis DFT (dx-sum split 4-way, quad reduce) + spectral mix.
// grid 64 = b(8)*kx(8); block 1024.
// ---------------------------------------------------------------------------
__global__ __launch_bounds__(1024) void k_fDmix(
    const float2* __restrict__ Bh,
    const float2* __restrict__ w1, const float2* __restrict__ w2,
    const float2* __restrict__ w3, const float2* __restrict__ w4,
    float2* __restrict__ O)
{
    BUILD_TW();
    __shared__ float2 Cs[256];   // [c][ky][kz] = c*32 + ky*4 + kz
    const int t = threadIdx.x, bid = blockIdx.x;
    const int b = bid >> 3, kx = bid & 7;
    const int kxv = kx < 4 ? kx : kx + 56;
    __syncthreads();
    {
        const int out = t >> 2, q = t & 3;
        const int kz = out & 3, ky = (out >> 2) & 7, c = out >> 5;
        const float2* Bp = Bh + (size_t)(b * 8 + c) * 2048 + ky * 4 + kz;
        float re = 0.f, im = 0.f;
        int ti = (kxv * q) & 63;
        const int step = (kxv * 4) & 63;
        #pragma unroll 4
        for (int i = 0; i < 16; ++i) {
            float2 v = Bp[(q + i * 4) * 32];
            float cc = twc[ti], ss = tws[ti];
            re += v.x * cc + v.y * ss;
            im += v.y * cc - v.x * ss;
            ti = (ti + step) & 63;
        }
        re = red4_quad(re);
        im = red4_quad(im);
        if (q == 0) Cs[out] = make_float2(re, im);
    }
    __syncthreads();
    if (t < 256) {
        int kz = t & 3, ky = (t >> 2) & 7, o = t >> 5;
        const float2* wsel = (kx < 4) ? ((ky < 4) ? w1 : w3) : ((ky < 4) ? w2 : w4);
        int kxw = kx & 3, kyw = ky & 3;
        float re = 0.f, im = 0.f;
        #pragma unroll
        for (int i = 0; i < 8; ++i) {
            float2 cv = Cs[i * 32 + ky * 4 + kz];
            float2 wv = wsel[(((size_t)(i * 8 + o) * 4 + kxw) * 4 + kyw) * 4 + kz];
            re += cv.x * wv.x - cv.y * wv.y;
            im += cv.x * wv.y + cv.y * wv.x;
        }
        O[(((size_t)(b * 8 + o) * 8 + kx) * 8 + ky) * 4 + kz] = make_float2(re, im);
    }
}

// ---------------------------------------------------------------------------
// Inverse D/H DFT in LDS + irfftW + conv + gelu + x in place + next-layer A.
// x and O prefetched at kernel top. grid 2048; block 256.
// ---------------------------------------------------------------------------
__global__ __launch_bounds__(256, 4) void k_ptA(
    float* __restrict__ x, const float2* __restrict__ O,
    const float* __restrict__ cw, const float* __restrict__ cb,
    float2* __restrict__ A)
{
    BUILD_TW();
    __shared__ float2 Ps[256];          // [o][ky][kz]
    __shared__ float2 Qs[8 * 16 * 4];   // [o][dyl][kz]
    const int t = threadIdx.x, bid = blockIdx.x;
    const int b = bid >> 8, dx = (bid >> 2) & 63, dy0 = (bid & 3) * 16;
    const int dyl = t >> 4, wq = t & 15;
    const size_t sp = (size_t)dx * 4096 + (size_t)(dy0 + dyl) * 64 + wq * 4;
    // ---- prefetch: all global loads issued before any barrier ----
    float4 xv[8];
    #pragma unroll
    for (int c = 0; c < 8; ++c)
        xv[c] = *(const float4*)&x[(size_t)(b * 8 + c) * 262144 + sp];
    const int pkz = t & 3, pky = (t >> 2) & 7, po = t >> 5;
    float2 ov[8];
    #pragma unroll
    for (int kxi = 0; kxi < 8; ++kxi)
        ov[kxi] = O[(((size_t)(b * 8 + po) * 8 + kxi) * 8 + pky) * 4 + pkz];
    __syncthreads();
    {   // Ps
        float re = 0.f, im = 0.f;
        #pragma unroll
        for (int kxi = 0; kxi < 8; ++kxi) {
            int kxv = kxi < 4 ? kxi : kxi + 56;
            int ti = (kxv * dx) & 63;
            float cc = twc[ti], ss = tws[ti];
            re += ov[kxi].x * cc - ov[kxi].y * ss;   // * e^{+i phi}
            im += ov[kxi].y * cc + ov[kxi].x * ss;
        }
        Ps[t] = make_float2(re, im);
    }
    __syncthreads();
    for (int it = t; it < 512; it += 256) {  // Qs
        int kz = it & 3, qdyl = (it >> 2) & 15, o = it >> 6;
        int dy = dy0 + qdyl;
        float re = 0.f, im = 0.f;
        #pragma unroll
        for (int kyi = 0; kyi < 8; ++kyi) {
            int kyv = kyi < 4 ? kyi : kyi + 56;
            int ti = (kyv * dy) & 63;
            float2 v = Ps[(o * 8 + kyi) * 4 + kz];
            float cc = twc[ti], ss = tws[ti];
            re += v.x * cc - v.y * ss;
            im += v.y * cc + v.x * ss;
        }
        Qs[(o * 16 + qdyl) * 4 + kz] = make_float2(re, im);
    }
    __syncthreads();
    float c1[4], s1[4], c2[4], s2[4], c3[4], s3[4];
    #pragma unroll
    for (int j = 0; j < 4; ++j) {
        int w = wq * 4 + j;
        c1[j] = twc[w];             s1[j] = tws[w];
        c2[j] = twc[(2 * w) & 63];  s2[j] = tws[(2 * w) & 63];
        c3[j] = twc[(3 * w) & 63];  s3[j] = tws[(3 * w) & 63];
    }
    const float invN3 = 1.0f / 262144.0f;
    #pragma unroll
    for (int o = 0; o < 8; ++o) {
        float4 qa = *(const float4*)&Qs[(o * 16 + dyl) * 4];      // q0,q1
        float4 qb = *(const float4*)&Qs[(o * 16 + dyl) * 4 + 2];  // q2,q3
        float outj[4];
        #pragma unroll
        for (int j = 0; j < 4; ++j) {
            float x1 = qa.x + 2.f * (qa.z * c1[j] - qa.w * s1[j]
                                   + qb.x * c2[j] - qb.y * s2[j]
                                   + qb.z * c3[j] - qb.w * s3[j]);
            x1 *= invN3;
            float x2 = cb[o];
            #pragma unroll
            for (int c = 0; c < 8; ++c) {
                const float* xc = &xv[c].x;
                x2 += cw[o * 8 + c] * xc[j];
            }
            outj[j] = gelu_fast(x1 + x2);
        }
        *(float4*)&x[(size_t)(b * 8 + o) * 262144 + sp] =
            make_float4(outj[0], outj[1], outj[2], outj[3]);
        a_tail_store(outj, c1, s1, c2, s2, c3, s3, wq,
                     A + ((size_t)(b * 8 + o) * 4096 + dx * 64 + dy0 + dyl) * 4);
    }
}

// ---------------------------------------------------------------------------
// Layer 3: inverse DFT + conv (no gelu) -> fc1+gelu+fc2, + hard core u*nu.
// Writes d_out only; x/u prefetched at top.
// ---------------------------------------------------------------------------
__global__ __launch_bounds__(256, 4) void k_ptout(
    const float* __restrict__ x, const float2* __restrict__ O,
    const float* __restrict__ cw, const float* __restrict__ cb,
    const float* __restrict__ u, const float* __restrict__ nu,
    const float* __restrict__ fc1w, const float* __restrict__ fc1b,
    const float* __restrict__ fc2w, const float* __restrict__ fc2b,
    float* __restrict__ out)
{
    BUILD_TW();
    __shared__ float2 Ps[256];
    __shared__ float2 Qs[8 * 16 * 4];
    const int t = threadIdx.x, bid = blockIdx.x;
    const int b = bid >> 8, dx = (bid >> 2) & 63, dy0 = (bid & 3) * 16;
    const int dyl = t >> 4, wq = t & 15;
    const size_t sp = (size_t)dx * 4096 + (size_t)(dy0 + dyl) * 64 + wq * 4;
    float4 xv[8];
    #pragma unroll
    for (int c = 0; c < 8; ++c)
        xv[c] = *(const float4*)&x[(size_t)(b * 8 + c) * 262144 + sp];
    float4 uv[3];
    #pragma unroll
    for (int c = 0; c < 3; ++c)
        uv[c] = *(const float4*)&u[(size_t)(b * 3 + c) * 262144 + sp];
    const int pkz = t & 3, pky = (t >> 2) & 7, po = t >> 5;
    float2 ovv[8];
    #pragma unroll
    for (int kxi = 0; kxi < 8; ++kxi)
        ovv[kxi] = O[(((size_t)(b * 8 + po) * 8 + kxi) * 8 + pky) * 4 + pkz];
    __syncthreads();
    {
        float re = 0.f, im = 0.f;
        #pragma unroll
        for (int kxi = 0; kxi < 8; ++kxi) {
            int kxv = kxi < 4 ? kxi : kxi + 56;
            int ti = (kxv * dx) & 63;
            float cc = twc[ti], ss = tws[ti];
            re += ovv[kxi].x * cc - ovv[kxi].y * ss;
            im += ovv[kxi].y * cc + ovv[kxi].x * ss;
        }
        Ps[t] = make_float2(re, im);
    }
    __syncthreads();
    for (int it = t; it < 512; it += 256) {
        int kz = it & 3, qdyl = (it >> 2) & 15, o = it >> 6;
        int dy = dy0 + qdyl;
        float re = 0.f, im = 0.f;
        #pragma unroll
        for (int kyi = 0; kyi < 8; ++kyi) {
            int kyv = kyi < 4 ? kyi : kyi + 56;
            int ti = (kyv * dy) & 63;
            float2 v = Ps[(o * 8 + kyi) * 4 + kz];
            float cc = twc[ti], ss = tws[ti];
            re += v.x * cc - v.y * ss;
            im += v.y * cc + v.x * ss;
        }
        Qs[(o * 16 + qdyl) * 4 + kz] = make_float2(re, im);
    }
    __syncthreads();
    float c1[4], s1[4], c2[4], s2[4], c3[4], s3[4];
    #pragma unroll
    for (int j = 0; j < 4; ++j) {
        int w = wq * 4 + j;
        c1[j] = twc[w];             s1[j] = tws[w];
        c2[j] = twc[(2 * w) & 63];  s2[j] = tws[(2 * w) & 63];
        c3[j] = twc[(3 * w) & 63];  s3[j] = tws[(3 * w) & 63];
    }
    const float invN3 = 1.0f / 262144.0f;
    float vv[8][4];   // layer-3 activations (no gelu)
    #pragma unroll
    for (int o = 0; o < 8; ++o) {
        float4 qa = *(const float4*)&Qs[(o * 16 + dyl) * 4];
        float4 qb = *(const float4*)&Qs[(o * 16 + dyl) * 4 + 2];
        #pragma unroll
        for (int j = 0; j < 4; ++j) {
            float x1 = qa.x + 2.f * (qa.z * c1[j] - qa.w * s1[j]
                                   + qb.x * c2[j] - qb.y * s2[j]
                                   + qb.z * c3[j] - qb.w * s3[j]);
            x1 *= invN3;
            float x2 = cb[o];
            #pragma unroll
            for (int c = 0; c < 8; ++c) {
                const float* xc = &xv[c].x;
                x2 += cw[o * 8 + c] * xc[j];
            }
            vv[o][j] = x1 + x2;
        }
    }
    float so[6][4];
    #pragma unroll
    for (int c6 = 0; c6 < 6; ++c6)
        #pragma unroll
        for (int j = 0; j < 4; ++j) so[c6][j] = fc2b[c6];
    #pragma unroll 4
    for (int h = 0; h < 32; ++h) {
        float wr[8];
        #pragma unroll
        for (int c = 0; c < 8; ++c) wr[c] = fc1w[h * 8 + c];   // uniform -> SGPR
        const float hb = fc1b[h];
        float w2r[6];
        #pragma unroll
        for (int c6 = 0; c6 < 6; ++c6) w2r[c6] = fc2w[c6 * 32 + h];
        #pragma unroll
        for (int j = 0; j < 4; ++j) {
            float a = hb;
            #pragma unroll
            for (int c = 0; c < 8; ++c) a += vv[c][j] * wr[c];
            float g = gelu_fast(a);
            #pragma unroll
            for (int c6 = 0; c6 < 6; ++c6) so[c6][j] += g * w2r[c6];
        }
    }
    const float nuv = nu[0];
    #pragma unroll
    for (int c6 = 0; c6 < 6; ++c6) {
        float4 res;
        float* rp = &res.x;
        if (c6 < 3) {
            const float* up = &uv[c6].x;
            #pragma unroll
            for (int j = 0; j < 4; ++j) rp[j] = 0.3f * so[c6][j] + up[j] * nuv;
        } else {
            #pragma unroll
            for (int j = 0; j < 4; ++j) rp[j] = 0.3f * so[c6][j];
        }
        *(float4*)&out[(size_t)(b * 6 + c6) * 262144 + sp] = res;
    }
}

// pack split re/im spectral leaves into interleaved float2, ALL 16 weights
// in one dispatch (pointers passed by value).
struct PackPtrs { const float* re[16]; const float* im[16]; };

__global__ __launch_bounds__(256) void k_pack_all(PackPtrs p, float2* __restrict__ dst)
{
    int i = blockIdx.x * 256 + threadIdx.x;   // 65536 = 16 * 4096
    int w = i >> 12, idx = i & 4095;
    dst[i] = make_float2(p.re[w][idx], p.im[w][idx]);
}

// ---------------------------------------------------------------------------
extern "C" void kernel_launch(void* const* d_in, const int* in_sizes, int n_in,
                              void* d_out, int out_size, void* d_ws, size_t ws_size,
                              hipStream_t stream)
{
    (void)out_size;
    const char* leaf[32];
    bool spec_split = false;
    const char* spec_re[16]; const char* spec_im[16];
    int src = 0;
    leaf[0] = (const char*)d_in[src++];
    leaf[1] = (const char*)d_in[src++];
    leaf[2] = (const char*)d_in[src++];
    leaf[3] = (const char*)d_in[src++];
    {
        int s = (src < n_in) ? in_sizes[src] : 4096;
        if (n_in >= 48 && s == 4096) {
            spec_split = true;
            for (int i = 0; i < 16; ++i) {
                spec_re[i] = (const char*)d_in[src++];
                spec_im[i] = (const char*)d_in[src++];
            }
        } else {
            int per;
            if (s == 4096 || s == 8192) per = 1;
            else if (s == 16384 || s == 32768) per = 4;
            else per = 16;
            for (int i = 0; i < 16; i += per) {
                const char* base = (const char*)d_in[src++];
                for (int j = 0; j < per; ++j) leaf[4 + i + j] = base + (size_t)j * 4096 * 8;
            }
        }
    }
    {
        int s = (src < n_in) ? in_sizes[src] : 64;
        if (s == 64) { for (int i = 0; i < 4; ++i) leaf[20 + i] = (const char*)d_in[src++]; }
        else { const char* base = (const char*)d_in[src++];
               for (int i = 0; i < 4; ++i) leaf[20 + i] = base + (size_t)i * 64 * 4; }
    }
    {
        int s = (src < n_in) ? in_sizes[src] : 8;
        if (s == 8) { for (int i = 0; i < 4; ++i) leaf[24 + i] = (const char*)d_in[src++]; }
        else { const char* base = (const char*)d_in[src++];
               for (int i = 0; i < 4; ++i) leaf[24 + i] = base + (size_t)i * 8 * 4; }
    }
    leaf[28] = (const char*)d_in[src++];
    leaf[29] = (const char*)d_in[src++];
    leaf[30] = (const char*)d_in[src++];
    leaf[31] = (const char*)d_in[src++];

    const float* u    = (const float*)leaf[0];
    const float* nu   = (const float*)leaf[1];
    const float* fc0w = (const float*)leaf[2];
    const float* fc0b = (const float*)leaf[3];
    const float* convw[4], *convb[4];
    for (int i = 0; i < 4; ++i) { convw[i] = (const float*)leaf[20 + i];
                                  convb[i] = (const float*)leaf[24 + i]; }
    const float* fc1w = (const float*)leaf[28];
    const float* fc1b = (const float*)leaf[29];
    const float* fc2w = (const float*)leaf[30];
    const float* fc2b = (const float*)leaf[31];

    // scratch: x | A | Bh | O | SP.  Fallback: A,Bh,SP in d_out (dead before
    // k_ptout writes it); O must stay in ws (live during k_ptout).
    const size_t szX = 67108864, szA = 8388608, szB = 1048576,
                 szO = 131072, szSP = 524288;
    char* ws = (char*)d_ws;
    float* xbuf = (float*)ws;
    float2 *Abuf, *Bbuf, *Obuf, *SP;
    if (ws_size >= szX + szA + szB + szO + szSP) {
        Abuf = (float2*)(ws + szX);
        Bbuf = (float2*)(ws + szX + szA);
        Obuf = (float2*)(ws + szX + szA + szB);
        SP   = (float2*)(ws + szX + szA + szB + szO);
    } else {
        Obuf = (float2*)(ws + szX);
        Abuf = (float2*)d_out;
        Bbuf = (float2*)((char*)d_out + szA);
        SP   = (float2*)((char*)d_out + szA + szB);
    }

    const float2* specw[16];
    if (spec_split) {
        PackPtrs pp;
        for (int i = 0; i < 16; ++i) {
            pp.re[i] = (const float*)spec_re[i];
            pp.im[i] = (const float*)spec_im[i];
            specw[i] = SP + (size_t)i * 4096;
        }
        hipLaunchKernelGGL(k_pack_all, dim3(256), dim3(256), 0, stream, pp, SP);
    } else {
        for (int i = 0; i < 16; ++i) specw[i] = (const float2*)leaf[4 + i];
    }
    float* outp = (float*)d_out;

    hipLaunchKernelGGL(k_liftA, dim3(2048), dim3(256), 0, stream, u, fc0w, fc0b, xbuf, Abuf);
    for (int L = 0; L < 4; ++L) {
        hipLaunchKernelGGL(k_fH, dim3(512), dim3(1024), 0, stream, Abuf, Bbuf);
        hipLaunchKernelGGL(k_fDmix, dim3(64), dim3(1024), 0, stream,
                           Bbuf, specw[L*4+0], specw[L*4+1], specw[L*4+2], specw[L*4+3], Obuf);
        if (L < 3) {
            hipLaunchKernelGGL(k_ptA, dim3(2048), dim3(256), 0, stream,
                               xbuf, Obuf, convw[L], convb[L], Abuf);
        } else {
            hipLaunchKernelGGL(k_ptout, dim3(2048), dim3(256), 0, stream,
                               xbuf, Obuf, convw[3], convb[3], u, nu,
                               fc1w, fc1b, fc2w, fc2b, outp);
        }
    }
}

// Round 5
// 282.519 us; speedup vs baseline: 2.5346x; 1.0436x over previous
//
#include <hip/hip_runtime.h>

// FNO3d forward, MI355X. Round 11:
//  - Aux kernels (k_fH, k_fDmix) reverted to exact R7 forms (best measured;
//    R10's rewrites were noise-neutral).
//  - Hot kernels (k_liftA, k_ptA, k_ptout) rewritten on float2 ext-vectors
//    over the j (spatial-pair) axis so the backend can form v_pk_fma_f32 /
//    v_pk_mul_f32: the fc1/fc2 loop, conv, irfftW, lift and a_tail dot
//    products all become packed fp32, ~40% fewer VALU instructions.
//
// Layouts:
//   x  : float [B=8][C=8][64][64][64]          (67,108,864 B)
//   A  : float2[8][8][dx=64][dy=64][kz=4]      ( 8,388,608 B)
//   Bh : float2[8][8][dx=64][ky=8][kz=4]       ( 1,048,576 B)
//   O  : float2[8][8][kx=8][ky=8][kz=4]        (   131,072 B)

#define TWO_PI_OVER_64 0.09817477042468103

typedef float v2f __attribute__((ext_vector_type(2)));

__device__ __forceinline__ float gelu_fast(float x) {
    float x2 = x * x;
    float p  = x * (1.0f + 0.044715f * x2);
    float e  = __builtin_amdgcn_exp2f(-2.3022083f * p);
    return x * __builtin_amdgcn_rcpf(1.0f + e);
}

__device__ __forceinline__ v2f gelu2(v2f x) {
    v2f x2 = x * x;
    v2f p  = x * (1.0f + 0.044715f * x2);
    v2f r;
    r.x = __builtin_amdgcn_rcpf(1.0f + __builtin_amdgcn_exp2f(-2.3022083f * p.x));
    r.y = __builtin_amdgcn_rcpf(1.0f + __builtin_amdgcn_exp2f(-2.3022083f * p.y));
    return x * r;
}

#define BUILD_TW() \
    __shared__ float twc[64], tws[64]; \
    if (threadIdx.x < 64) { \
        double a_ = TWO_PI_OVER_64 * (double)threadIdx.x; \
        twc[threadIdx.x] = (float)cos(a_); tws[threadIdx.x] = (float)sin(a_); \
    }

// Twiddle pair registers for the W-axis (w = wq*4 + {0..3}), packed by j-pair.
#define LOAD_WTW() \
    v2f c1p[2], s1p[2], c2p[2], s2p[2], c3p[2], s3p[2]; \
    _Pragma("unroll") \
    for (int p = 0; p < 2; ++p) { \
        int wa = wq * 4 + 2 * p, wb = wa + 1; \
        c1p[p] = (v2f){twc[wa], twc[wb]}; \
        s1p[p] = (v2f){tws[wa], tws[wb]}; \
        c2p[p] = (v2f){twc[(2 * wa) & 63], twc[(2 * wb) & 63]}; \
        s2p[p] = (v2f){tws[(2 * wa) & 63], tws[(2 * wb) & 63]}; \
        c3p[p] = (v2f){twc[(3 * wa) & 63], twc[(3 * wb) & 63]}; \
        s3p[p] = (v2f){tws[(3 * wa) & 63], tws[(3 * wb) & 63]}; \
    }

// DPP row_ror rotation-add: after steps 1,2,4,8 every lane of each 16-lane
// row holds the row sum. VALU-only (no ds_bpermute / LDS pipe).
#define ROR_STEP(x, CTRL) \
    x += __int_as_float(__builtin_amdgcn_update_dpp( \
            0, __float_as_int(x), CTRL, 0xF, 0xF, true))

__device__ __forceinline__ float red16_ror(float x) {
    ROR_STEP(x, 0x121);   // row_ror:1
    ROR_STEP(x, 0x122);   // row_ror:2
    ROR_STEP(x, 0x124);   // row_ror:4
    ROR_STEP(x, 0x128);   // row_ror:8
    return x;
}

// A-tail: partial W-DFT over this lane's 4 w-points (as 2 packed pairs),
// DPP reduce across the 16 wq-lanes, predicated float4 store.
__device__ __forceinline__ void a_tail_store(
    const v2f v[2], const v2f c1[2], const v2f s1[2],
    const v2f c2[2], const v2f s2[2], const v2f c3[2], const v2f s3[2],
    int wq, float2* __restrict__ Arow)
{
    v2f d;
    d = v[0] + v[1];               float p0  = d.x + d.y;
    d = v[0]*c1[0] + v[1]*c1[1];   float ar1 = d.x + d.y;
    d = v[0]*s1[0] + v[1]*s1[1];   float ai1 = -(d.x + d.y);
    d = v[0]*c2[0] + v[1]*c2[1];   float ar2 = d.x + d.y;
    d = v[0]*s2[0] + v[1]*s2[1];   float ai2 = -(d.x + d.y);
    d = v[0]*c3[0] + v[1]*c3[1];   float ar3 = d.x + d.y;
    d = v[0]*s3[0] + v[1]*s3[1];   float ai3 = -(d.x + d.y);
    p0  = red16_ror(p0);
    ar1 = red16_ror(ar1);  ai1 = red16_ror(ai1);
    ar2 = red16_ror(ar2);  ai2 = red16_ror(ai2);
    ar3 = red16_ror(ar3);  ai3 = red16_ror(ai3);
    if (wq < 2) {
        float4 av;
        av.x = (wq == 0) ? p0   : ar2;
        av.y = (wq == 0) ? 0.f  : ai2;
        av.z = (wq == 0) ? ar1  : ar3;
        av.w = (wq == 0) ? ai1  : ai3;
        *((float4*)Arow + wq) = av;
    }
}

// ---------------------------------------------------------------------------
// Lift (3->8 ch) + forward W-DFT (DPP tail), packed fp32.
// grid 2048 = b(8)*dx(64)*dyq(4); block 256 (dyl = t>>4, wq = t&15).
// ---------------------------------------------------------------------------
__global__ __launch_bounds__(256) void k_liftA(
    const float* __restrict__ u, const float* __restrict__ fc0w,
    const float* __restrict__ fc0b, float* __restrict__ x,
    float2* __restrict__ A)
{
    BUILD_TW();
    const int t = threadIdx.x, bid = blockIdx.x;
    const int b = bid >> 8, dx = (bid >> 2) & 63, dy0 = (bid & 3) * 16;
    const int dyl = t >> 4, wq = t & 15;
    const size_t sp = (size_t)dx * 4096 + (size_t)(dy0 + dyl) * 64 + wq * 4;
    v2f uin[3][2];
    #pragma unroll
    for (int c = 0; c < 3; ++c) {
        float4 v = *(const float4*)&u[(size_t)(b * 3 + c) * 262144 + sp];
        uin[c][0] = (v2f){v.x, v.y};
        uin[c][1] = (v2f){v.z, v.w};
    }
    __syncthreads();
    LOAD_WTW();
    #pragma unroll
    for (int o = 0; o < 8; ++o) {
        float w0 = fc0w[o * 3 + 0], w1 = fc0w[o * 3 + 1], w2 = fc0w[o * 3 + 2];
        float bb = fc0b[o];
        v2f vp[2];
        #pragma unroll
        for (int p = 0; p < 2; ++p)
            vp[p] = bb + uin[0][p] * w0 + uin[1][p] * w1 + uin[2][p] * w2;
        *(float4*)&x[(size_t)(b * 8 + o) * 262144 + sp] =
            make_float4(vp[0].x, vp[0].y, vp[1].x, vp[1].y);
        a_tail_store(vp, c1p, s1p, c2p, s2p, c3p, s3p, wq,
                     A + ((size_t)(b * 8 + o) * 4096 + dx * 64 + dy0 + dyl) * 4);
    }
}

// ---------------------------------------------------------------------------
// H-axis DFT: A[b,c,dx,dy,kz] -> Bh[b,c,dx,ky,kz]. grid 512, block 256. (R7)
// ---------------------------------------------------------------------------
__global__ __launch_bounds__(256) void k_fH(const float2* __restrict__ A,
                                            float2* __restrict__ Bh)
{
    BUILD_TW();
    __syncthreads();
    const int g = blockIdx.x * 256 + threadIdx.x;
    const int triple = g >> 5, idx = g & 31;
    const int ky = idx >> 2, kz = idx & 3;
    const int b = triple >> 9, c = (triple >> 6) & 7, dx = triple & 63;
    const int kyv = ky < 4 ? ky : ky + 56;
    const float2* Ap = A + (size_t)(b * 8 + c) * 16384 + dx * 256 + kz;
    float re = 0.f, im = 0.f;
    int ti = 0;
    #pragma unroll 8
    for (int dy = 0; dy < 64; ++dy) {
        float2 a = Ap[dy * 4];
        float cc = twc[ti], ss = tws[ti];
        re += a.x * cc + a.y * ss;   // * e^{-i phi}
        im += a.y * cc - a.x * ss;
        ti = (ti + kyv) & 63;
    }
    Bh[(size_t)(b * 8 + c) * 2048 + dx * 32 + ky * 4 + kz] = make_float2(re, im);
}

// ---------------------------------------------------------------------------
// D-axis DFT (into LDS) + spectral mix. grid 64, block 256. (R7)
// ---------------------------------------------------------------------------
__global__ __launch_bounds__(256) void k_fDmix(
    const float2* __restrict__ Bh,
    const float2* __restrict__ w1, const float2* __restrict__ w2,
    const float2* __restrict__ w3, const float2* __restrict__ w4,
    float2* __restrict__ O)
{
    BUILD_TW();
    __shared__ float2 Cs[256];   // [c][ky][kz] = c*32 + ky*4 + kz
    const int t = threadIdx.x, bid = blockIdx.x;
    const int b = bid >> 3, kx = bid & 7;
    const int kxv = kx < 4 ? kx : kx + 56;
    __syncthreads();
    {
        int kz = t & 3, ky = (t >> 2) & 7, c = t >> 5;
        const float2* Bp = Bh + (size_t)(b * 8 + c) * 2048 + ky * 4 + kz;
        float re = 0.f, im = 0.f;
        int ti = 0;
        #pragma unroll 8
        for (int dx = 0; dx < 64; ++dx) {
            float2 v = Bp[dx * 32];
            float cc = twc[ti], ss = tws[ti];
            re += v.x * cc + v.y * ss;
            im += v.y * cc - v.x * ss;
            ti = (ti + kxv) & 63;
        }
        Cs[t] = make_float2(re, im);
    }
    __syncthreads();
    {
        int kz = t & 3, ky = (t >> 2) & 7, o = t >> 5;
        const float2* wsel = (kx < 4) ? ((ky < 4) ? w1 : w3) : ((ky < 4) ? w2 : w4);
        int kxw = kx & 3, kyw = ky & 3;
        float re = 0.f, im = 0.f;
        #pragma unroll
        for (int i = 0; i < 8; ++i) {
            float2 cv = Cs[i * 32 + ky * 4 + kz];
            float2 wv = wsel[(((size_t)(i * 8 + o) * 4 + kxw) * 4 + kyw) * 4 + kz];
            re += cv.x * wv.x - cv.y * wv.y;
            im += cv.x * wv.y + cv.y * wv.x;
        }
        O[(((size_t)(b * 8 + o) * 8 + kx) * 8 + ky) * 4 + kz] = make_float2(re, im);
    }
}

// ---------------------------------------------------------------------------
// Inverse D/H DFT in LDS + irfftW + conv + gelu + x in place + next-layer A.
// Packed fp32 over the j-pairs. grid 2048; block 256.
// ---------------------------------------------------------------------------
__global__ __launch_bounds__(256, 4) void k_ptA(
    float* __restrict__ x, const float2* __restrict__ O,
    const float* __restrict__ cw, const float* __restrict__ cb,
    float2* __restrict__ A)
{
    BUILD_TW();
    __shared__ float2 Ps[256];          // [o][ky][kz]
    __shared__ float2 Qs[8 * 16 * 4];   // [o][dyl][kz]
    const int t = threadIdx.x, bid = blockIdx.x;
    const int b = bid >> 8, dx = (bid >> 2) & 63, dy0 = (bid & 3) * 16;
    const int dyl = t >> 4, wq = t & 15;
    const size_t sp = (size_t)dx * 4096 + (size_t)(dy0 + dyl) * 64 + wq * 4;
    // ---- prefetch: all global loads issued before any barrier ----
    float4 xv[8];
    #pragma unroll
    for (int c = 0; c < 8; ++c)
        xv[c] = *(const float4*)&x[(size_t)(b * 8 + c) * 262144 + sp];
    const int pkz = t & 3, pky = (t >> 2) & 7, po = t >> 5;
    float2 ov[8];
    #pragma unroll
    for (int kxi = 0; kxi < 8; ++kxi)
        ov[kxi] = O[(((size_t)(b * 8 + po) * 8 + kxi) * 8 + pky) * 4 + pkz];
    __syncthreads();
    {   // Ps
        float re = 0.f, im = 0.f;
        #pragma unroll
        for (int kxi = 0; kxi < 8; ++kxi) {
            int kxv = kxi < 4 ? kxi : kxi + 56;
            int ti = (kxv * dx) & 63;
            float cc = twc[ti], ss = tws[ti];
            re += ov[kxi].x * cc - ov[kxi].y * ss;   // * e^{+i phi}
            im += ov[kxi].y * cc + ov[kxi].x * ss;
        }
        Ps[t] = make_float2(re, im);
    }
    __syncthreads();
    for (int it = t; it < 512; it += 256) {  // Qs
        int kz = it & 3, qdyl = (it >> 2) & 15, o = it >> 6;
        int dy = dy0 + qdyl;
        float re = 0.f, im = 0.f;
        #pragma unroll
        for (int kyi = 0; kyi < 8; ++kyi) {
            int kyv = kyi < 4 ? kyi : kyi + 56;
            int ti = (kyv * dy) & 63;
            float2 v = Ps[(o * 8 + kyi) * 4 + kz];
            float cc = twc[ti], ss = tws[ti];
            re += v.x * cc - v.y * ss;
            im += v.y * cc + v.x * ss;
        }
        Qs[(o * 16 + qdyl) * 4 + kz] = make_float2(re, im);
    }
    __syncthreads();
    LOAD_WTW();
    const float invN3 = 1.0f / 262144.0f;
    #pragma unroll
    for (int o = 0; o < 8; ++o) {
        float4 qa = *(const float4*)&Qs[(o * 16 + dyl) * 4];      // q0,q1
        float4 qb = *(const float4*)&Qs[(o * 16 + dyl) * 4 + 2];  // q2,q3
        const float cbo = cb[o];
        v2f outp[2];
        #pragma unroll
        for (int p = 0; p < 2; ++p) {
            v2f x1 = qa.x + 2.f * (qa.z * c1p[p] - qa.w * s1p[p]
                                 + qb.x * c2p[p] - qb.y * s2p[p]
                                 + qb.z * c3p[p] - qb.w * s3p[p]);
            x1 *= invN3;
            v2f x2 = (v2f){cbo, cbo};
            #pragma unroll
            for (int c = 0; c < 8; ++c) {
                const v2f* xp = (const v2f*)&xv[c];
                x2 += cw[o * 8 + c] * xp[p];
            }
            outp[p] = gelu2(x1 + x2);
        }
        *(float4*)&x[(size_t)(b * 8 + o) * 262144 + sp] =
            make_float4(outp[0].x, outp[0].y, outp[1].x, outp[1].y);
        a_tail_store(outp, c1p, s1p, c2p, s2p, c3p, s3p, wq,
                     A + ((size_t)(b * 8 + o) * 4096 + dx * 64 + dy0 + dyl) * 4);
    }
}

// ---------------------------------------------------------------------------
// Layer 3: inverse DFT + conv (no gelu) -> fc1+gelu+fc2, + hard core u*nu.
// Packed fp32 over the j-pairs. Writes d_out only. grid 2048; block 256.
// ---------------------------------------------------------------------------
__global__ __launch_bounds__(256, 4) void k_ptout(
    const float* __restrict__ x, const float2* __restrict__ O,
    const float* __restrict__ cw, const float* __restrict__ cb,
    const float* __restrict__ u, const float* __restrict__ nu,
    const float* __restrict__ fc1w, const float* __restrict__ fc1b,
    const float* __restrict__ fc2w, const float* __restrict__ fc2b,
    float* __restrict__ out)
{
    BUILD_TW();
    __shared__ float2 Ps[256];
    __shared__ float2 Qs[8 * 16 * 4];
    const int t = threadIdx.x, bid = blockIdx.x;
    const int b = bid >> 8, dx = (bid >> 2) & 63, dy0 = (bid & 3) * 16;
    const int dyl = t >> 4, wq = t & 15;
    const size_t sp = (size_t)dx * 4096 + (size_t)(dy0 + dyl) * 64 + wq * 4;
    float4 xv[8];
    #pragma unroll
    for (int c = 0; c < 8; ++c)
        xv[c] = *(const float4*)&x[(size_t)(b * 8 + c) * 262144 + sp];
    float4 uv[3];
    #pragma unroll
    for (int c = 0; c < 3; ++c)
        uv[c] = *(const float4*)&u[(size_t)(b * 3 + c) * 262144 + sp];
    const int pkz = t & 3, pky = (t >> 2) & 7, po = t >> 5;
    float2 ovv[8];
    #pragma unroll
    for (int kxi = 0; kxi < 8; ++kxi)
        ovv[kxi] = O[(((size_t)(b * 8 + po) * 8 + kxi) * 8 + pky) * 4 + pkz];
    __syncthreads();
    {
        float re = 0.f, im = 0.f;
        #pragma unroll
        for (int kxi = 0; kxi < 8; ++kxi) {
            int kxv = kxi < 4 ? kxi : kxi + 56;
            int ti = (kxv * dx) & 63;
            float cc = twc[ti], ss = tws[ti];
            re += ovv[kxi].x * cc - ovv[kxi].y * ss;
            im += ovv[kxi].y * cc + ovv[kxi].x * ss;
        }
        Ps[t] = make_float2(re, im);
    }
    __syncthreads();
    for (int it = t; it < 512; it += 256) {
        int kz = it & 3, qdyl = (it >> 2) & 15, o = it >> 6;
        int dy = dy0 + qdyl;
        float re = 0.f, im = 0.f;
        #pragma unroll
        for (int kyi = 0; kyi < 8; ++kyi) {
            int kyv = kyi < 4 ? kyi : kyi + 56;
            int ti = (kyv * dy) & 63;
            float2 v = Ps[(o * 8 + kyi) * 4 + kz];
            float cc = twc[ti], ss = tws[ti];
            re += v.x * cc - v.y * ss;
            im += v.y * cc + v.x * ss;
        }
        Qs[(o * 16 + qdyl) * 4 + kz] = make_float2(re, im);
    }
    __syncthreads();
    LOAD_WTW();
    const float invN3 = 1.0f / 262144.0f;
    v2f vvp[8][2];   // layer-3 activations (no gelu), packed j-pairs
    #pragma unroll
    for (int o = 0; o < 8; ++o) {
        float4 qa = *(const float4*)&Qs[(o * 16 + dyl) * 4];
        float4 qb = *(const float4*)&Qs[(o * 16 + dyl) * 4 + 2];
        const float cbo = cb[o];
        #pragma unroll
        for (int p = 0; p < 2; ++p) {
            v2f x1 = qa.x + 2.f * (qa.z * c1p[p] - qa.w * s1p[p]
                                 + qb.x * c2p[p] - qb.y * s2p[p]
                                 + qb.z * c3p[p] - qb.w * s3p[p]);
            x1 *= invN3;
            v2f x2 = (v2f){cbo, cbo};
            #pragma unroll
            for (int c = 0; c < 8; ++c) {
                const v2f* xp = (const v2f*)&xv[c];
                x2 += cw[o * 8 + c] * xp[p];
            }
            vvp[o][p] = x1 + x2;
        }
    }
    v2f so2[6][2];
    #pragma unroll
    for (int c6 = 0; c6 < 6; ++c6) {
        float bb = fc2b[c6];
        so2[c6][0] = (v2f){bb, bb};
        so2[c6][1] = (v2f){bb, bb};
    }
    #pragma unroll 4
    for (int h = 0; h < 32; ++h) {
        float wr[8];
        #pragma unroll
        for (int c = 0; c < 8; ++c) wr[c] = fc1w[h * 8 + c];   // uniform -> SGPR
        const float hb = fc1b[h];
        float w2r[6];
        #pragma unroll
        for (int c6 = 0; c6 < 6; ++c6) w2r[c6] = fc2w[c6 * 32 + h];
        #pragma unroll
        for (int p = 0; p < 2; ++p) {
            v2f a = (v2f){hb, hb};
            #pragma unroll
            for (int c = 0; c < 8; ++c) a += vvp[c][p] * wr[c];
            v2f g = gelu2(a);
            #pragma unroll
            for (int c6 = 0; c6 < 6; ++c6) so2[c6][p] += g * w2r[c6];
        }
    }
    const float nuv = nu[0];
    #pragma unroll
    for (int c6 = 0; c6 < 6; ++c6) {
        v2f r0 = 0.3f * so2[c6][0];
        v2f r1 = 0.3f * so2[c6][1];
        if (c6 < 3) {
            const v2f* up = (const v2f*)&uv[c6];
            r0 += up[0] * nuv;
            r1 += up[1] * nuv;
        }
        *(float4*)&out[(size_t)(b * 6 + c6) * 262144 + sp] =
            make_float4(r0.x, r0.y, r1.x, r1.y);
    }
}

// pack split re/im spectral leaves into interleaved float2, ALL 16 weights
// in one dispatch (pointers passed by value).
struct PackPtrs { const float* re[16]; const float* im[16]; };

__global__ __launch_bounds__(256) void k_pack_all(PackPtrs p, float2* __restrict__ dst)
{
    int i = blockIdx.x * 256 + threadIdx.x;   // 65536 = 16 * 4096
    int w = i >> 12, idx = i & 4095;
    dst[i] = make_float2(p.re[w][idx], p.im[w][idx]);
}

// ---------------------------------------------------------------------------
extern "C" void kernel_launch(void* const* d_in, const int* in_sizes, int n_in,
                              void* d_out, int out_size, void* d_ws, size_t ws_size,
                              hipStream_t stream)
{
    (void)out_size;
    const char* leaf[32];
    bool spec_split = false;
    const char* spec_re[16]; const char* spec_im[16];
    int src = 0;
    leaf[0] = (const char*)d_in[src++];
    leaf[1] = (const char*)d_in[src++];
    leaf[2] = (const char*)d_in[src++];
    leaf[3] = (const char*)d_in[src++];
    {
        int s = (src < n_in) ? in_sizes[src] : 4096;
        if (n_in >= 48 && s == 4096) {
            spec_split = true;
            for (int i = 0; i < 16; ++i) {
                spec_re[i] = (const char*)d_in[src++];
                spec_im[i] = (const char*)d_in[src++];
            }
        } else {
            int per;
            if (s == 4096 || s == 8192) per = 1;
            else if (s == 16384 || s == 32768) per = 4;
            else per = 16;
            for (int i = 0; i < 16; i += per) {
                const char* base = (const char*)d_in[src++];
                for (int j = 0; j < per; ++j) leaf[4 + i + j] = base + (size_t)j * 4096 * 8;
            }
        }
    }
    {
        int s = (src < n_in) ? in_sizes[src] : 64;
        if (s == 64) { for (int i = 0; i < 4; ++i) leaf[20 + i] = (const char*)d_in[src++]; }
        else { const char* base = (const char*)d_in[src++];
               for (int i = 0; i < 4; ++i) leaf[20 + i] = base + (size_t)i * 64 * 4; }
    }
    {
        int s = (src < n_in) ? in_sizes[src] : 8;
        if (s == 8) { for (int i = 0; i < 4; ++i) leaf[24 + i] = (const char*)d_in[src++]; }
        else { const char* base = (const char*)d_in[src++];
               for (int i = 0; i < 4; ++i) leaf[24 + i] = base + (size_t)i * 8 * 4; }
    }
    leaf[28] = (const char*)d_in[src++];
    leaf[29] = (const char*)d_in[src++];
    leaf[30] = (const char*)d_in[src++];
    leaf[31] = (const char*)d_in[src++];

    const float* u    = (const float*)leaf[0];
    const float* nu   = (const float*)leaf[1];
    const float* fc0w = (const float*)leaf[2];
    const float* fc0b = (const float*)leaf[3];
    const float* convw[4], *convb[4];
    for (int i = 0; i < 4; ++i) { convw[i] = (const float*)leaf[20 + i];
                                  convb[i] = (const float*)leaf[24 + i]; }
    const float* fc1w = (const float*)leaf[28];
    const float* fc1b = (const float*)leaf[29];
    const float* fc2w = (const float*)leaf[30];
    const float* fc2b = (const float*)leaf[31];

    // scratch: x | A | Bh | O | SP.  Fallback: A,Bh,SP in d_out (dead before
    // k_ptout writes it); O must stay in ws (live during k_ptout).
    const size_t szX = 67108864, szA = 8388608, szB = 1048576,
                 szO = 131072, szSP = 524288;
    char* ws = (char*)d_ws;
    float* xbuf = (float*)ws;
    float2 *Abuf, *Bbuf, *Obuf, *SP;
    if (ws_size >= szX + szA + szB + szO + szSP) {
        Abuf = (float2*)(ws + szX);
        Bbuf = (float2*)(ws + szX + szA);
        Obuf = (float2*)(ws + szX + szA + szB);
        SP   = (float2*)(ws + szX + szA + szB + szO);
    } else {
        Obuf = (float2*)(ws + szX);
        Abuf = (float2*)d_out;
        Bbuf = (float2*)((char*)d_out + szA);
        SP   = (float2*)((char*)d_out + szA + szB);
    }

    const float2* specw[16];
    if (spec_split) {
        PackPtrs pp;
        for (int i = 0; i < 16; ++i) {
            pp.re[i] = (const float*)spec_re[i];
            pp.im[i] = (const float*)spec_im[i];
            specw[i] = SP + (size_t)i * 4096;
        }
        hipLaunchKernelGGL(k_pack_all, dim3(256), dim3(256), 0, stream, pp, SP);
    } else {
        for (int i = 0; i < 16; ++i) specw[i] = (const float2*)leaf[4 + i];
    }
    float* outp = (float*)d_out;

    hipLaunchKernelGGL(k_liftA, dim3(2048), dim3(256), 0, stream, u, fc0w, fc0b, xbuf, Abuf);
    for (int L = 0; L < 4; ++L) {
        hipLaunchKernelGGL(k_fH, dim3(512), dim3(256), 0, stream, Abuf, Bbuf);
        hipLaunchKernelGGL(k_fDmix, dim3(64), dim3(256), 0, stream,
                           Bbuf, specw[L*4+0], specw[L*4+1], specw[L*4+2], specw[L*4+3], Obuf);
        if (L < 3) {
            hipLaunchKernelGGL(k_ptA, dim3(2048), dim3(256), 0, stream,
                               xbuf, Obuf, convw[L], convb[L], Abuf);
        } else {
            hipLaunchKernelGGL(k_ptout, dim3(2048), dim3(256), 0, stream,
                               xbuf, Obuf, convw[3], convb[3], u, nu,
                               fc1w, fc1b, fc2w, fc2b, outp);
        }
    }
}